// Round 1
// baseline (886.592 us; speedup 1.0000x reference)
//
#include <hip/hip_runtime.h>
#include <math.h>

#define NEG_SLOPE 0.2f
#define BN_EPS 1e-5f

static __device__ __forceinline__ float leaky(float v) { return v > 0.f ? v : NEG_SLOPE * v; }

// ---------------- setup: degree + loop_attr sums ----------------
__global__ void k_edge_stats(const int* __restrict__ dst, const float* __restrict__ eattr,
                             int* __restrict__ degInt, float* __restrict__ loopSum, int E) {
  int e = blockIdx.x * blockDim.x + threadIdx.x;
  if (e >= E) return;
  int d = dst[e];
  atomicAdd(&degInt[d], 1);
#pragma unroll
  for (int k = 0; k < 7; k++) atomicAdd(&loopSum[d * 7 + k], eattr[e * 7 + k]);
}

// single-block exclusive scan of degInt -> rowStart[0..n], rowStart[n]=total
__global__ void k_scan(const int* __restrict__ degInt, int* __restrict__ rowStart, int n) {
  __shared__ int sums[1024];
  int tid = threadIdx.x;
  int per = (n + 1023) / 1024;
  int start = tid * per;
  int end = start + per; if (end > n) end = n;
  int s = 0;
  for (int i = start; i < end; i++) s += degInt[i];
  sums[tid] = s;
  __syncthreads();
  for (int off = 1; off < 1024; off <<= 1) {
    int v = (tid >= off) ? sums[tid - off] : 0;
    __syncthreads();
    sums[tid] += v;
    __syncthreads();
  }
  int base = (tid > 0) ? sums[tid - 1] : 0;
  for (int i = start; i < end; i++) { rowStart[i] = base; base += degInt[i]; }
  if (tid == 1023) rowStart[n] = sums[1023];
}

__global__ void k_fill_csr(const int* __restrict__ src, const int* __restrict__ dst,
                           const int* __restrict__ rowStart, int* __restrict__ cursor,
                           int* __restrict__ csrSrc, int* __restrict__ csrEid, int E) {
  int e = blockIdx.x * blockDim.x + threadIdx.x;
  if (e >= E) return;
  int d = dst[e];
  int pos = rowStart[d] + atomicAdd(&cursor[d], 1);
  csrSrc[pos] = src[e];
  csrEid[pos] = e;
}

__global__ void k_loop_attr(const int* __restrict__ degInt, float* __restrict__ loopSum, int Nn) {
  int i = blockIdx.x * blockDim.x + threadIdx.x;
  if (i >= Nn * 7) return;
  int n = i / 7;
  float dg = (float)degInt[n];
  loopSum[i] = loopSum[i] / fmaxf(dg, 1.0f);
}

// ---------------- GEMM: C[M,Nc] = A[M,K] @ B[K,Nc] (f32, K % 16 == 0) ----------------
#define TM 64
#define TN 64
#define TK 16
__global__ __launch_bounds__(256) void k_gemm(const float* __restrict__ A, const float* __restrict__ B,
                                              float* __restrict__ C, int M, int K, int Nc) {
  __shared__ float As[TK][TM + 1];
  __shared__ float Bs[TK][TN];
  int bm = blockIdx.x * TM;
  int bn = blockIdx.y * TN;
  int tid = threadIdx.x;
  int tr = tid / 16, tc = tid % 16;
  float acc[4][4] = {};
  for (int k0 = 0; k0 < K; k0 += TK) {
    for (int i = tid; i < TM * TK; i += 256) {
      int m = i / TK, kk = i % TK;
      int gm = bm + m;
      float v = 0.f;
      if (gm < M) v = A[(size_t)gm * K + k0 + kk];
      As[kk][m] = v;
    }
    for (int i = tid; i < TK * TN; i += 256) {
      int kk = i / TN, nn = i % TN;
      int gn = bn + nn;
      float v = 0.f;
      if (gn < Nc) v = B[(size_t)(k0 + kk) * Nc + gn];
      Bs[kk][nn] = v;
    }
    __syncthreads();
#pragma unroll
    for (int kk = 0; kk < TK; kk++) {
      float a[4], b[4];
#pragma unroll
      for (int i = 0; i < 4; i++) a[i] = As[kk][tr * 4 + i];
#pragma unroll
      for (int j = 0; j < 4; j++) b[j] = Bs[kk][tc * 4 + j];
#pragma unroll
      for (int i = 0; i < 4; i++)
#pragma unroll
        for (int j = 0; j < 4; j++) acc[i][j] += a[i] * b[j];
    }
    __syncthreads();
  }
  for (int i = 0; i < 4; i++) {
    int gm = bm + tr * 4 + i;
    if (gm >= M) continue;
    for (int j = 0; j < 4; j++) {
      int gn = bn + tc * 4 + j;
      if (gn < Nc) C[(size_t)gm * Nc + gn] = acc[i][j];
    }
  }
}

// ---------------- per-(node,head) attention dots (one wave each) ----------------
__global__ __launch_bounds__(64) void k_attn_nd(const float* __restrict__ hbuf,
                                                const float* __restrict__ a_s, const float* __restrict__ a_d,
                                                float* __restrict__ asrc, float* __restrict__ adst,
                                                int Nn, int H, int C) {
  int idx = blockIdx.x;
  int n = idx / H, h = idx % H;
  int lane = threadIdx.x;
  float s1 = 0.f, s2 = 0.f;
  for (int c = lane; c < C; c += 64) {
    float v = hbuf[(size_t)n * H * C + h * C + c];
    s1 += v * a_s[h * C + c];
    s2 += v * a_d[h * C + c];
  }
  for (int off = 32; off > 0; off >>= 1) { s1 += __shfl_xor(s1, off); s2 += __shfl_xor(s2, off); }
  if (lane == 0) { asrc[idx] = s1; adst[idx] = s2; }
}

// w_att[d,h] = sum_c We[d, h*C+c] * a_e[h,c]   (7*H values)
__global__ void k_watt(const float* __restrict__ We, const float* __restrict__ a_e,
                       float* __restrict__ w_att, int H, int C) {
  int t = threadIdx.x;
  if (t >= 7 * H) return;
  int d = t / H, h = t % H;
  float s = 0.f;
  for (int c = 0; c < C; c++) s += We[(size_t)d * H * C + h * C + c] * a_e[h * C + c];
  w_att[d * H + h] = s;
}

__global__ void k_edge_logit(const int* __restrict__ src, const int* __restrict__ dst,
                             const float* __restrict__ eattr,
                             const float* __restrict__ asrc, const float* __restrict__ adst,
                             const float* __restrict__ w_att, float* __restrict__ logitE,
                             int E, int H) {
  int i = blockIdx.x * blockDim.x + threadIdx.x;
  if (i >= E * H) return;
  int e = i / H, h = i % H;
  float ae = 0.f;
#pragma unroll
  for (int d7 = 0; d7 < 7; d7++) ae += eattr[e * 7 + d7] * w_att[d7 * H + h];
  float v = asrc[src[e] * H + h] + adst[dst[e] * H + h] + ae;
  logitE[i] = leaky(v);
}

__global__ void k_self_logit(const float* __restrict__ loopAttr, const float* __restrict__ w_att,
                             const float* __restrict__ asrc, const float* __restrict__ adst,
                             float* __restrict__ lself, int Nn, int H) {
  int i = blockIdx.x * blockDim.x + threadIdx.x;
  if (i >= Nn * H) return;
  int n = i / H, h = i % H;
  float ae = 0.f;
#pragma unroll
  for (int d = 0; d < 7; d++) ae += loopAttr[n * 7 + d] * w_att[d * H + h];
  logit: ;
  float v = asrc[i] + adst[i] + ae;
  lself[i] = leaky(v);
}

// ---------------- per-node gather: softmax + weighted sum + bias + BN + ReLU ----------------
template <int H, int C>
__global__ __launch_bounds__(64) void k_gather(
    const int* __restrict__ rowStart, const int* __restrict__ csrSrc, const int* __restrict__ csrEid,
    const float* __restrict__ logitE, const float* __restrict__ lself,
    const float* __restrict__ hbuf, const float* __restrict__ bias,
    const float* __restrict__ bng, const float* __restrict__ bnb,
    const float* __restrict__ bnrm, const float* __restrict__ bnrv,
    float* __restrict__ outbuf, int Nn) {
  constexpr int HC = H * C;
  constexpr int R = (HC + 63) / 64;
  int n = blockIdx.x;
  if (n >= Nn) return;
  int lane = threadIdx.x;
  int r0 = rowStart[n], r1 = rowStart[n + 1];

  float ls[H], m[H], den[H];
#pragma unroll
  for (int h = 0; h < H; h++) ls[h] = lself[n * H + h];

  // phase A1: max
  float lm[H];
#pragma unroll
  for (int h = 0; h < H; h++) lm[h] = -1e30f;
  for (int j = r0 + lane; j < r1; j += 64) {
    int eid = csrEid[j];
#pragma unroll
    for (int h = 0; h < H; h++) lm[h] = fmaxf(lm[h], logitE[eid * H + h]);
  }
#pragma unroll
  for (int h = 0; h < H; h++) {
    float v = lm[h];
    for (int off = 32; off > 0; off >>= 1) v = fmaxf(v, __shfl_xor(v, off));
    m[h] = fmaxf(v, ls[h]);
  }
  // phase A2: denominator
  float ld[H];
#pragma unroll
  for (int h = 0; h < H; h++) ld[h] = 0.f;
  for (int j = r0 + lane; j < r1; j += 64) {
    int eid = csrEid[j];
#pragma unroll
    for (int h = 0; h < H; h++) ld[h] += __expf(logitE[eid * H + h] - m[h]);
  }
#pragma unroll
  for (int h = 0; h < H; h++) {
    float v = ld[h];
    for (int off = 32; off > 0; off >>= 1) v += __shfl_xor(v, off);
    den[h] = v + __expf(ls[h] - m[h]);
  }

  // phase B: accumulate p * h[src]
  float acc[R];
#pragma unroll
  for (int r = 0; r < R; r++) acc[r] = 0.f;
  for (int j = r0; j < r1; j++) {
    int eid = csrEid[j];
    int s = csrSrc[j];
    float p[H];
#pragma unroll
    for (int h = 0; h < H; h++) p[h] = __expf(logitE[eid * H + h] - m[h]);
    const float* hrow = hbuf + (size_t)s * HC;
#pragma unroll
    for (int r = 0; r < R; r++) {
      int c = r * 64 + lane;
      if (c < HC) acc[r] += p[(r * 64) / C] * hrow[c];
    }
  }
  {  // self loop
    float ps[H];
#pragma unroll
    for (int h = 0; h < H; h++) ps[h] = __expf(ls[h] - m[h]);
    const float* hrow = hbuf + (size_t)n * HC;
#pragma unroll
    for (int r = 0; r < R; r++) {
      int c = r * 64 + lane;
      if (c < HC) acc[r] += ps[(r * 64) / C] * hrow[c];
    }
  }
  // epilogue: normalize + bias + BN + ReLU
#pragma unroll
  for (int r = 0; r < R; r++) {
    int c = r * 64 + lane;
    if (c >= HC) continue;
    float v = acc[r] / den[(r * 64) / C] + bias[c];
    v = (v - bnrm[c]) * (bng[c] * rsqrtf(bnrv[c] + BN_EPS)) + bnb[c];
    outbuf[(size_t)n * HC + c] = fmaxf(v, 0.f);
  }
}

// ---------------- pooling ----------------
__global__ void k_pool(const float* __restrict__ h3, const int* __restrict__ batch,
                       float* __restrict__ meanSum, unsigned int* __restrict__ maxKey,
                       int* __restrict__ count, int Nn) {
  int i = blockIdx.x * blockDim.x + threadIdx.x;
  if (i >= Nn * 32) return;
  int n = i >> 5, c = i & 31;
  int g = batch[n];
  float v = h3[i];
  atomicAdd(&meanSum[g * 32 + c], v);
  atomicMax(&maxKey[g * 32 + c], __float_as_uint(v));  // v >= 0 -> bit-monotone
  if (c == 0) atomicAdd(&count[g], 1);
}

__global__ __launch_bounds__(64) void k_mlp(const float* __restrict__ meanSum,
                                            const unsigned int* __restrict__ maxKey,
                                            const int* __restrict__ count,
                                            const float* __restrict__ lw1, const float* __restrict__ lb1,
                                            const float* __restrict__ lw2, const float* __restrict__ lb2,
                                            float* __restrict__ out, int NG) {
  int g = blockIdx.x;
  int t = threadIdx.x;
  __shared__ float z[64];
  __shared__ float z1[32];
  float cnt = fmaxf((float)count[g], 1.0f);
  if (t < 32) z[t] = meanSum[g * 32 + t] / cnt;
  else        z[t] = __uint_as_float(maxKey[g * 32 + (t - 32)]);
  __syncthreads();
  if (t < 32) {
    float s = lb1[t];
    for (int k = 0; k < 64; k++) s += z[k] * lw1[k * 32 + t];
    z1[t] = fmaxf(s, 0.f);
  }
  __syncthreads();
  if (t == 0) {
    float s = lb2[0];
    for (int j = 0; j < 32; j++) s += z1[j] * lw2[j];
    out[g] = 1.f / (1.f + expf(-s));
  }
}

// ---------------- driver ----------------
extern "C" void kernel_launch(void* const* d_in, const int* in_sizes, int n_in,
                              void* d_out, int out_size, void* d_ws, size_t ws_size,
                              hipStream_t stream) {
  const float* x     = (const float*)d_in[0];
  const int*   eidx  = (const int*)d_in[1];
  const float* eattr = (const float*)d_in[2];
  const int*   batch = (const int*)d_in[3];
  int N = in_sizes[0] / 64;
  int E = in_sizes[1] / 2;
  int NG = out_size;
  const int* src = eidx;
  const int* dst = eidx + E;

  const float* W[3]  = {(const float*)d_in[4],  (const float*)d_in[14], (const float*)d_in[24]};
  const float* AS[3] = {(const float*)d_in[5],  (const float*)d_in[15], (const float*)d_in[25]};
  const float* AD[3] = {(const float*)d_in[6],  (const float*)d_in[16], (const float*)d_in[26]};
  const float* WE[3] = {(const float*)d_in[7],  (const float*)d_in[17], (const float*)d_in[27]};
  const float* AE[3] = {(const float*)d_in[8],  (const float*)d_in[18], (const float*)d_in[28]};
  const float* B[3]  = {(const float*)d_in[9],  (const float*)d_in[19], (const float*)d_in[29]};
  const float* G[3]  = {(const float*)d_in[10], (const float*)d_in[20], (const float*)d_in[30]};
  const float* BT[3] = {(const float*)d_in[11], (const float*)d_in[21], (const float*)d_in[31]};
  const float* RM[3] = {(const float*)d_in[12], (const float*)d_in[22], (const float*)d_in[32]};
  const float* RV[3] = {(const float*)d_in[13], (const float*)d_in[23], (const float*)d_in[33]};
  const float* lw1 = (const float*)d_in[34];
  const float* lb1 = (const float*)d_in[35];
  const float* lw2 = (const float*)d_in[36];
  const float* lb2 = (const float*)d_in[37];

  char* wp = (char*)d_ws;
  auto alloc = [&](size_t bytes) -> void* {
    void* p = (void*)wp;
    wp += (bytes + 255) & ~(size_t)255;
    return p;
  };
  float* bufA     = (float*)alloc((size_t)N * 512 * 4);
  float* bufH     = (float*)alloc((size_t)N * 512 * 4);
  int*   degInt   = (int*)alloc((size_t)N * 4);
  int*   cursor   = (int*)alloc((size_t)N * 4);
  int*   rowStart = (int*)alloc((size_t)(N + 1) * 4);
  float* loopAttr = (float*)alloc((size_t)N * 7 * 4);
  int*   csrSrc   = (int*)alloc((size_t)E * 4);
  int*   csrEid   = (int*)alloc((size_t)E * 4);
  float* logitE   = (float*)alloc((size_t)E * 4 * 4);
  float* asrc     = (float*)alloc((size_t)N * 4 * 4);
  float* adst     = (float*)alloc((size_t)N * 4 * 4);
  float* lself    = (float*)alloc((size_t)N * 4 * 4);
  float* watt     = (float*)alloc(32 * 4);
  float* meanSum  = (float*)alloc((size_t)NG * 32 * 4);
  unsigned int* maxKey = (unsigned int*)alloc((size_t)NG * 32 * 4);
  int*   count    = (int*)alloc((size_t)NG * 4);

  hipMemsetAsync(degInt, 0, (size_t)N * 4, stream);
  hipMemsetAsync(cursor, 0, (size_t)N * 4, stream);
  hipMemsetAsync(loopAttr, 0, (size_t)N * 7 * 4, stream);
  hipMemsetAsync(meanSum, 0, (size_t)NG * 32 * 4, stream);
  hipMemsetAsync(maxKey, 0, (size_t)NG * 32 * 4, stream);
  hipMemsetAsync(count, 0, (size_t)NG * 4, stream);

  k_edge_stats<<<(E + 255) / 256, 256, 0, stream>>>(dst, eattr, degInt, loopAttr, E);
  k_scan<<<1, 1024, 0, stream>>>(degInt, rowStart, N);
  k_fill_csr<<<(E + 255) / 256, 256, 0, stream>>>(src, dst, rowStart, cursor, csrSrc, csrEid, E);
  k_loop_attr<<<(N * 7 + 255) / 256, 256, 0, stream>>>(degInt, loopAttr, N);

  const int CinA[3] = {64, 512, 256};
  const int Hh[3]   = {4, 4, 1};
  const int Cc[3]   = {128, 64, 32};
  const float* in = x;
  for (int L = 0; L < 3; L++) {
    int H = Hh[L], C = Cc[L], HC = H * C, K = CinA[L];
    k_gemm<<<dim3((N + TM - 1) / TM, (HC + TN - 1) / TN), 256, 0, stream>>>(in, W[L], bufH, N, K, HC);
    k_attn_nd<<<N * H, 64, 0, stream>>>(bufH, AS[L], AD[L], asrc, adst, N, H, C);
    k_watt<<<1, 32, 0, stream>>>(WE[L], AE[L], watt, H, C);
    k_edge_logit<<<(E * H + 255) / 256, 256, 0, stream>>>(src, dst, eattr, asrc, adst, watt, logitE, E, H);
    k_self_logit<<<(N * H + 255) / 256, 256, 0, stream>>>(loopAttr, watt, asrc, adst, lself, N, H);
    if (L == 0)
      k_gather<4, 128><<<N, 64, 0, stream>>>(rowStart, csrSrc, csrEid, logitE, lself, bufH,
                                             B[L], G[L], BT[L], RM[L], RV[L], bufA, N);
    else if (L == 1)
      k_gather<4, 64><<<N, 64, 0, stream>>>(rowStart, csrSrc, csrEid, logitE, lself, bufH,
                                            B[L], G[L], BT[L], RM[L], RV[L], bufA, N);
    else
      k_gather<1, 32><<<N, 64, 0, stream>>>(rowStart, csrSrc, csrEid, logitE, lself, bufH,
                                            B[L], G[L], BT[L], RM[L], RV[L], bufA, N);
    in = bufA;
  }

  k_pool<<<((size_t)N * 32 + 255) / 256, 256, 0, stream>>>(bufA, batch, meanSum, maxKey, count, N);
  k_mlp<<<NG, 64, 0, stream>>>(meanSum, maxKey, count, lw1, lb1, lw2, lb2, (float*)d_out, NG);
}

// Round 2
// 567.094 us; speedup vs baseline: 1.5634x; 1.5634x over previous
//
#include <hip/hip_runtime.h>
#include <math.h>

#define NEG_SLOPE 0.2f
#define BN_EPS 1e-5f

typedef __attribute__((ext_vector_type(8))) short bf16x8;
typedef __attribute__((ext_vector_type(4))) float f32x4;
typedef unsigned short u16;
typedef __attribute__((ext_vector_type(8))) unsigned short u16x8;
typedef __attribute__((ext_vector_type(4))) unsigned short u16x4;

static __device__ __forceinline__ float leaky(float v) { return v > 0.f ? v : NEG_SLOPE * v; }
static __device__ __forceinline__ float b2f(u16 b) { return __uint_as_float(((unsigned)b) << 16); }
static __device__ __forceinline__ u16 f2b(float f) {
  unsigned u = __float_as_uint(f);
  u += 0x7FFF + ((u >> 16) & 1);
  return (u16)(u >> 16);
}

// ---------------- setup: degree + loop_attr sums ----------------
__global__ void k_edge_stats(const int* __restrict__ dst, const float* __restrict__ eattr,
                             int* __restrict__ degInt, float* __restrict__ loopSum, int E) {
  int e = blockIdx.x * blockDim.x + threadIdx.x;
  if (e >= E) return;
  int d = dst[e];
  atomicAdd(&degInt[d], 1);
#pragma unroll
  for (int k = 0; k < 7; k++) atomicAdd(&loopSum[d * 7 + k], eattr[e * 7 + k]);
}

__global__ void k_scan(const int* __restrict__ degInt, int* __restrict__ rowStart, int n) {
  __shared__ int sums[1024];
  int tid = threadIdx.x;
  int per = (n + 1023) / 1024;
  int start = tid * per;
  int end = start + per; if (end > n) end = n;
  int s = 0;
  for (int i = start; i < end; i++) s += degInt[i];
  sums[tid] = s;
  __syncthreads();
  for (int off = 1; off < 1024; off <<= 1) {
    int v = (tid >= off) ? sums[tid - off] : 0;
    __syncthreads();
    sums[tid] += v;
    __syncthreads();
  }
  int base = (tid > 0) ? sums[tid - 1] : 0;
  for (int i = start; i < end; i++) { rowStart[i] = base; base += degInt[i]; }
  if (tid == 1023) rowStart[n] = sums[1023];
}

__global__ void k_fill_csr(const int* __restrict__ src, const int* __restrict__ dst,
                           const int* __restrict__ rowStart, int* __restrict__ cursor,
                           int* __restrict__ csrSrc, int* __restrict__ csrEid, int E) {
  int e = blockIdx.x * blockDim.x + threadIdx.x;
  if (e >= E) return;
  int d = dst[e];
  int pos = rowStart[d] + atomicAdd(&cursor[d], 1);
  csrSrc[pos] = src[e];
  csrEid[pos] = e;
}

__global__ void k_loop_attr(const int* __restrict__ degInt, float* __restrict__ loopSum, int Nn) {
  int i = blockIdx.x * blockDim.x + threadIdx.x;
  if (i >= Nn * 7) return;
  int n = i / 7;
  float dg = (float)degInt[n];
  loopSum[i] = loopSum[i] / fmaxf(dg, 1.0f);
}

// ---------------- casts ----------------
__global__ void k_cast_bf16(const float* __restrict__ in, u16* __restrict__ out, int n) {
  int i = blockIdx.x * blockDim.x + threadIdx.x;
  if (i < n) out[i] = f2b(in[i]);
}

// W [K][N] f32 -> Wt [N][K] bf16
__global__ void k_transpose_cast(const float* __restrict__ W, u16* __restrict__ Wt, int K, int N) {
  int i = blockIdx.x * blockDim.x + threadIdx.x;
  if (i >= K * N) return;
  int k = i / N, n = i % N;
  Wt[(size_t)n * K + k] = f2b(W[i]);
}

// ---------------- MFMA bf16 GEMM: C[M,N] = A[M,K] @ Bt[N,K]^T ----------------
template <int BM, int BN, int WM, int WN>
__global__ __launch_bounds__(256) void k_gemm_mfma(const u16* __restrict__ A,
                                                   const u16* __restrict__ Bt,
                                                   u16* __restrict__ Cout,
                                                   int M, int K, int N) {
  constexpr int BK = 64;
  constexpr int LDT = BK + 8;  // +16B pad: row stride 144B -> 2-way bank alias (free)
  __shared__ u16 As[BM][LDT];
  __shared__ u16 Bs[BN][LDT];
  constexpr int NWN = BN / WN;
  constexpr int M_REP = WM / 16;
  constexpr int N_REP = WN / 16;
  int tid = threadIdx.x;
  int wid = tid >> 6, lane = tid & 63;
  int wr = wid / NWN, wc = wid % NWN;
  int bm = blockIdx.x * BM, bn = blockIdx.y * BN;
  int l15 = lane & 15, l4 = lane >> 4;

  f32x4 acc[M_REP][N_REP];
#pragma unroll
  for (int m = 0; m < M_REP; m++)
#pragma unroll
    for (int n = 0; n < N_REP; n++) acc[m][n] = (f32x4){0.f, 0.f, 0.f, 0.f};

  for (int k0 = 0; k0 < K; k0 += BK) {
    constexpr int CHA = BM * BK / 8;
#pragma unroll
    for (int ch0 = 0; ch0 < CHA; ch0 += 256) {
      int ch = ch0 + tid;
      int row = ch >> 3, cc = (ch & 7) * 8;
      int gr = bm + row;
      bf16x8 v = {};
      if (gr < M) v = *(const bf16x8*)(A + (size_t)gr * K + k0 + cc);
      *(bf16x8*)(&As[row][cc]) = v;
    }
    constexpr int CHB = BN * BK / 8;
#pragma unroll
    for (int ch0 = 0; ch0 < CHB; ch0 += 256) {
      int ch = ch0 + tid;
      int row = ch >> 3, cc = (ch & 7) * 8;
      int gr = bn + row;
      bf16x8 v = {};
      if (gr < N) v = *(const bf16x8*)(Bt + (size_t)gr * K + k0 + cc);
      *(bf16x8*)(&Bs[row][cc]) = v;
    }
    __syncthreads();
#pragma unroll
    for (int ks = 0; ks < BK; ks += 32) {
      bf16x8 af[M_REP], bfr[N_REP];
#pragma unroll
      for (int m = 0; m < M_REP; m++)
        af[m] = *(const bf16x8*)(&As[wr * WM + m * 16 + l15][ks + l4 * 8]);
#pragma unroll
      for (int n = 0; n < N_REP; n++)
        bfr[n] = *(const bf16x8*)(&Bs[wc * WN + n * 16 + l15][ks + l4 * 8]);
#pragma unroll
      for (int m = 0; m < M_REP; m++)
#pragma unroll
        for (int n = 0; n < N_REP; n++)
          acc[m][n] = __builtin_amdgcn_mfma_f32_16x16x32_bf16(af[m], bfr[n], acc[m][n], 0, 0, 0);
    }
    __syncthreads();
  }
  // C/D layout: col = lane&15, row = (lane>>4)*4 + reg
#pragma unroll
  for (int m = 0; m < M_REP; m++) {
#pragma unroll
    for (int r = 0; r < 4; r++) {
      int grow = bm + wr * WM + m * 16 + l4 * 4 + r;
      if (grow >= M) continue;
#pragma unroll
      for (int n = 0; n < N_REP; n++) {
        int gcol = bn + wc * WN + n * 16 + l15;
        Cout[(size_t)grow * N + gcol] = f2b(acc[m][n][r]);
      }
    }
  }
}

// ---------------- per-(node,head) attention dots ----------------
__global__ __launch_bounds__(64) void k_attn_nd(const u16* __restrict__ hbuf,
                                                const float* __restrict__ a_s, const float* __restrict__ a_d,
                                                float* __restrict__ asrc, float* __restrict__ adst,
                                                int Nn, int H, int C) {
  int idx = blockIdx.x;
  int n = idx / H, h = idx % H;
  int lane = threadIdx.x;
  float s1 = 0.f, s2 = 0.f;
  for (int c = lane; c < C; c += 64) {
    float v = b2f(hbuf[(size_t)n * H * C + h * C + c]);
    s1 += v * a_s[h * C + c];
    s2 += v * a_d[h * C + c];
  }
  for (int off = 32; off > 0; off >>= 1) { s1 += __shfl_xor(s1, off); s2 += __shfl_xor(s2, off); }
  if (lane == 0) { asrc[idx] = s1; adst[idx] = s2; }
}

__global__ void k_watt(const float* __restrict__ We, const float* __restrict__ a_e,
                       float* __restrict__ w_att, int H, int C) {
  int t = threadIdx.x;
  if (t >= 7 * H) return;
  int d = t / H, h = t % H;
  float s = 0.f;
  for (int c = 0; c < C; c++) s += We[(size_t)d * H * C + h * C + c] * a_e[h * C + c];
  w_att[d * H + h] = s;
}

template <int H>
__global__ void k_edge_logit(const int* __restrict__ src, const int* __restrict__ dst,
                             const float* __restrict__ eattr,
                             const float* __restrict__ asrc, const float* __restrict__ adst,
                             const float* __restrict__ w_att, float* __restrict__ logitE, int E) {
  int e = blockIdx.x * blockDim.x + threadIdx.x;
  if (e >= E) return;
  float ea[7];
#pragma unroll
  for (int d = 0; d < 7; d++) ea[d] = eattr[e * 7 + d];
  int s = src[e], dn = dst[e];
#pragma unroll
  for (int h = 0; h < H; h++) {
    float ae = 0.f;
#pragma unroll
    for (int d = 0; d < 7; d++) ae += ea[d] * w_att[d * H + h];
    logitE[e * H + h] = leaky(asrc[s * H + h] + adst[dn * H + h] + ae);
  }
}

template <int H>
__global__ void k_self_logit(const float* __restrict__ loopAttr, const float* __restrict__ w_att,
                             const float* __restrict__ asrc, const float* __restrict__ adst,
                             float* __restrict__ lself, int Nn) {
  int n = blockIdx.x * blockDim.x + threadIdx.x;
  if (n >= Nn) return;
  float la[7];
#pragma unroll
  for (int d = 0; d < 7; d++) la[d] = loopAttr[n * 7 + d];
#pragma unroll
  for (int h = 0; h < H; h++) {
    float ae = 0.f;
#pragma unroll
    for (int d = 0; d < 7; d++) ae += la[d] * w_att[d * H + h];
    lself[n * H + h] = leaky(asrc[n * H + h] + adst[n * H + h] + ae);
  }
}

// ---------------- gather (H=4): softmax + weighted sum + bias + BN + ReLU ----------------
// CPL cols per lane; c = lane*CPL + j; head = lane>>4 (valid for C=128/CPL=8 and C=64/CPL=4)
template <int C, int CPL>
__global__ __launch_bounds__(64) void k_gather4(
    const int* __restrict__ rowStart, const int* __restrict__ csrSrc, const int* __restrict__ csrEid,
    const float* __restrict__ logitE, const float* __restrict__ lself,
    const u16* __restrict__ hbuf, const float* __restrict__ bias,
    const float* __restrict__ bng, const float* __restrict__ bnb,
    const float* __restrict__ bnrm, const float* __restrict__ bnrv,
    u16* __restrict__ outbuf, int Nn) {
  constexpr int HC = 4 * C;
  typedef __attribute__((ext_vector_type(CPL))) unsigned short u16v;
  int n = blockIdx.x;
  if (n >= Nn) return;
  int lane = threadIdx.x;
  int r0 = rowStart[n], r1 = rowStart[n + 1];
  int hs = lane >> 4;

  float ls[4];
#pragma unroll
  for (int h = 0; h < 4; h++) ls[h] = lself[n * 4 + h];

  const f32x4* L4 = (const f32x4*)logitE;

  // phase A1: per-head max
  float m[4];
#pragma unroll
  for (int h = 0; h < 4; h++) m[h] = -1e30f;
  for (int j = r0 + lane; j < r1; j += 64) {
    f32x4 lv = L4[csrEid[j]];
#pragma unroll
    for (int h = 0; h < 4; h++) m[h] = fmaxf(m[h], lv[h]);
  }
#pragma unroll
  for (int h = 0; h < 4; h++) {
    float v = m[h];
    for (int off = 32; off > 0; off >>= 1) v = fmaxf(v, __shfl_xor(v, off));
    m[h] = fmaxf(v, ls[h]);
  }
  // phase A2: denominator
  float den[4];
#pragma unroll
  for (int h = 0; h < 4; h++) den[h] = 0.f;
  for (int j = r0 + lane; j < r1; j += 64) {
    f32x4 lv = L4[csrEid[j]];
#pragma unroll
    for (int h = 0; h < 4; h++) den[h] += __expf(lv[h] - m[h]);
  }
#pragma unroll
  for (int h = 0; h < 4; h++) {
    float v = den[h];
    for (int off = 32; off > 0; off >>= 1) v += __shfl_xor(v, off);
    den[h] = v + __expf(ls[h] - m[h]);
  }
  float mh = hs == 0 ? m[0] : hs == 1 ? m[1] : hs == 2 ? m[2] : m[3];
  float dh = hs == 0 ? den[0] : hs == 1 ? den[1] : hs == 2 ? den[2] : den[3];
  float lsh = hs == 0 ? ls[0] : hs == 1 ? ls[1] : hs == 2 ? ls[2] : ls[3];

  // phase B: acc += p * h[src], 2 edges in flight
  float acc[CPL];
#pragma unroll
  for (int j = 0; j < CPL; j++) acc[j] = 0.f;
  int j = r0;
  for (; j + 1 < r1; j += 2) {
    int e0 = csrEid[j], s0 = csrSrc[j];
    int e1 = csrEid[j + 1], s1 = csrSrc[j + 1];
    float lg0 = logitE[e0 * 4 + hs];
    float lg1 = logitE[e1 * 4 + hs];
    u16v h0 = *(const u16v*)(hbuf + (size_t)s0 * HC + lane * CPL);
    u16v h1 = *(const u16v*)(hbuf + (size_t)s1 * HC + lane * CPL);
    float p0 = __expf(lg0 - mh), p1 = __expf(lg1 - mh);
#pragma unroll
    for (int jj = 0; jj < CPL; jj++) acc[jj] += p0 * b2f(h0[jj]) + p1 * b2f(h1[jj]);
  }
  if (j < r1) {
    int e0 = csrEid[j], s0 = csrSrc[j];
    float p0 = __expf(logitE[e0 * 4 + hs] - mh);
    u16v h0 = *(const u16v*)(hbuf + (size_t)s0 * HC + lane * CPL);
#pragma unroll
    for (int jj = 0; jj < CPL; jj++) acc[jj] += p0 * b2f(h0[jj]);
  }
  {  // self loop
    float ps = __expf(lsh - mh);
    u16v hN = *(const u16v*)(hbuf + (size_t)n * HC + lane * CPL);
#pragma unroll
    for (int jj = 0; jj < CPL; jj++) acc[jj] += ps * b2f(hN[jj]);
  }
  // epilogue
  u16v ov;
#pragma unroll
  for (int jj = 0; jj < CPL; jj++) {
    int c = lane * CPL + jj;
    float v = acc[jj] / dh + bias[c];
    v = (v - bnrm[c]) * (bng[c] * rsqrtf(bnrv[c] + BN_EPS)) + bnb[c];
    ov[jj] = f2b(fmaxf(v, 0.f));
  }
  *(u16v*)(outbuf + (size_t)n * HC + lane * CPL) = ov;
}

// ---------------- gather (H=1, C=32): two edges in parallel across wave halves ----------------
__global__ __launch_bounds__(64) void k_gather_L3(
    const int* __restrict__ rowStart, const int* __restrict__ csrSrc, const int* __restrict__ csrEid,
    const float* __restrict__ logitE, const float* __restrict__ lself,
    const u16* __restrict__ hbuf, const float* __restrict__ bias,
    const float* __restrict__ bng, const float* __restrict__ bnb,
    const float* __restrict__ bnrm, const float* __restrict__ bnrv,
    u16* __restrict__ outbuf, int Nn) {
  int n = blockIdx.x;
  if (n >= Nn) return;
  int lane = threadIdx.x;
  int cl = lane & 31, half = lane >> 5;
  int r0 = rowStart[n], r1 = rowStart[n + 1];
  float ls = lself[n];

  float m = -1e30f;
  for (int j = r0 + lane; j < r1; j += 64) m = fmaxf(m, logitE[csrEid[j]]);
  for (int off = 32; off > 0; off >>= 1) m = fmaxf(m, __shfl_xor(m, off));
  m = fmaxf(m, ls);
  float den = 0.f;
  for (int j = r0 + lane; j < r1; j += 64) den += __expf(logitE[csrEid[j]] - m);
  for (int off = 32; off > 0; off >>= 1) den += __shfl_xor(den, off);
  den += __expf(ls - m);

  float acc = 0.f;
  for (int j = r0 + half; j < r1; j += 2) {
    int eid = csrEid[j], s = csrSrc[j];
    float p = __expf(logitE[eid] - m);
    acc += p * b2f(hbuf[(size_t)s * 32 + cl]);
  }
  if (half == 0) acc += __expf(ls - m) * b2f(hbuf[(size_t)n * 32 + cl]);
  acc += __shfl_xor(acc, 32);
  if (half == 0) {
    float v = acc / den + bias[cl];
    v = (v - bnrm[cl]) * (bng[cl] * rsqrtf(bnrv[cl] + BN_EPS)) + bnb[cl];
    outbuf[(size_t)n * 32 + cl] = f2b(fmaxf(v, 0.f));
  }
}

// ---------------- pooling ----------------
__global__ void k_pool(const u16* __restrict__ h3, const int* __restrict__ batch,
                       float* __restrict__ meanSum, unsigned int* __restrict__ maxKey,
                       int* __restrict__ count, int Nn) {
  int i = blockIdx.x * blockDim.x + threadIdx.x;
  if (i >= Nn * 32) return;
  int n = i >> 5, c = i & 31;
  int g = batch[n];
  float v = b2f(h3[i]);
  atomicAdd(&meanSum[g * 32 + c], v);
  atomicMax(&maxKey[g * 32 + c], __float_as_uint(v));  // v >= 0 -> bit-monotone
  if (c == 0) atomicAdd(&count[g], 1);
}

__global__ __launch_bounds__(64) void k_mlp(const float* __restrict__ meanSum,
                                            const unsigned int* __restrict__ maxKey,
                                            const int* __restrict__ count,
                                            const float* __restrict__ lw1, const float* __restrict__ lb1,
                                            const float* __restrict__ lw2, const float* __restrict__ lb2,
                                            float* __restrict__ out, int NG) {
  int g = blockIdx.x;
  int t = threadIdx.x;
  __shared__ float z[64];
  __shared__ float z1[32];
  float cnt = fmaxf((float)count[g], 1.0f);
  if (t < 32) z[t] = meanSum[g * 32 + t] / cnt;
  else        z[t] = __uint_as_float(maxKey[g * 32 + (t - 32)]);
  __syncthreads();
  if (t < 32) {
    float s = lb1[t];
    for (int k = 0; k < 64; k++) s += z[k] * lw1[k * 32 + t];
    z1[t] = fmaxf(s, 0.f);
  }
  __syncthreads();
  if (t == 0) {
    float s = lb2[0];
    for (int j = 0; j < 32; j++) s += z1[j] * lw2[j];
    out[g] = 1.f / (1.f + expf(-s));
  }
}

// ---------------- driver ----------------
extern "C" void kernel_launch(void* const* d_in, const int* in_sizes, int n_in,
                              void* d_out, int out_size, void* d_ws, size_t ws_size,
                              hipStream_t stream) {
  const float* x     = (const float*)d_in[0];
  const int*   eidx  = (const int*)d_in[1];
  const float* eattr = (const float*)d_in[2];
  const int*   batch = (const int*)d_in[3];
  int N = in_sizes[0] / 64;
  int E = in_sizes[1] / 2;
  int NG = out_size;
  const int* src = eidx;
  const int* dst = eidx + E;

  const float* W[3]  = {(const float*)d_in[4],  (const float*)d_in[14], (const float*)d_in[24]};
  const float* AS[3] = {(const float*)d_in[5],  (const float*)d_in[15], (const float*)d_in[25]};
  const float* AD[3] = {(const float*)d_in[6],  (const float*)d_in[16], (const float*)d_in[26]};
  const float* WE[3] = {(const float*)d_in[7],  (const float*)d_in[17], (const float*)d_in[27]};
  const float* AE[3] = {(const float*)d_in[8],  (const float*)d_in[18], (const float*)d_in[28]};
  const float* B[3]  = {(const float*)d_in[9],  (const float*)d_in[19], (const float*)d_in[29]};
  const float* G[3]  = {(const float*)d_in[10], (const float*)d_in[20], (const float*)d_in[30]};
  const float* BT[3] = {(const float*)d_in[11], (const float*)d_in[21], (const float*)d_in[31]};
  const float* RM[3] = {(const float*)d_in[12], (const float*)d_in[22], (const float*)d_in[32]};
  const float* RV[3] = {(const float*)d_in[13], (const float*)d_in[23], (const float*)d_in[33]};
  const float* lw1 = (const float*)d_in[34];
  const float* lb1 = (const float*)d_in[35];
  const float* lw2 = (const float*)d_in[36];
  const float* lb2 = (const float*)d_in[37];

  char* wp = (char*)d_ws;
  auto alloc = [&](size_t bytes) -> void* {
    void* p = (void*)wp;
    wp += (bytes + 255) & ~(size_t)255;
    return p;
  };
  u16*   xbf      = (u16*)alloc((size_t)N * 64 * 2);
  u16*   bufH     = (u16*)alloc((size_t)N * 512 * 2);
  u16*   bufA     = (u16*)alloc((size_t)N * 512 * 2);
  u16*   Wt1      = (u16*)alloc((size_t)512 * 64 * 2);
  u16*   Wt2      = (u16*)alloc((size_t)256 * 512 * 2);
  u16*   Wt3      = (u16*)alloc((size_t)32 * 256 * 2);
  int*   degInt   = (int*)alloc((size_t)N * 4);
  int*   cursor   = (int*)alloc((size_t)N * 4);
  int*   rowStart = (int*)alloc((size_t)(N + 1) * 4);
  float* loopAttr = (float*)alloc((size_t)N * 7 * 4);
  int*   csrSrc   = (int*)alloc((size_t)E * 4);
  int*   csrEid   = (int*)alloc((size_t)E * 4);
  float* logitE   = (float*)alloc((size_t)E * 4 * 4);
  float* asrc     = (float*)alloc((size_t)N * 4 * 4);
  float* adst     = (float*)alloc((size_t)N * 4 * 4);
  float* lself    = (float*)alloc((size_t)N * 4 * 4);
  float* watt     = (float*)alloc(32 * 4);
  float* meanSum  = (float*)alloc((size_t)NG * 32 * 4);
  unsigned int* maxKey = (unsigned int*)alloc((size_t)NG * 32 * 4);
  int*   count    = (int*)alloc((size_t)NG * 4);

  hipMemsetAsync(degInt, 0, (size_t)N * 4, stream);
  hipMemsetAsync(cursor, 0, (size_t)N * 4, stream);
  hipMemsetAsync(loopAttr, 0, (size_t)N * 7 * 4, stream);
  hipMemsetAsync(meanSum, 0, (size_t)NG * 32 * 4, stream);
  hipMemsetAsync(maxKey, 0, (size_t)NG * 32 * 4, stream);
  hipMemsetAsync(count, 0, (size_t)NG * 4, stream);

  // setup
  k_edge_stats<<<(E + 255) / 256, 256, 0, stream>>>(dst, eattr, degInt, loopAttr, E);
  k_scan<<<1, 1024, 0, stream>>>(degInt, rowStart, N);
  k_fill_csr<<<(E + 255) / 256, 256, 0, stream>>>(src, dst, rowStart, cursor, csrSrc, csrEid, E);
  k_loop_attr<<<(N * 7 + 255) / 256, 256, 0, stream>>>(degInt, loopAttr, N);
  k_cast_bf16<<<(N * 64 + 255) / 256, 256, 0, stream>>>(x, xbf, N * 64);
  k_transpose_cast<<<(64 * 512 + 255) / 256, 256, 0, stream>>>(W[0], Wt1, 64, 512);
  k_transpose_cast<<<(512 * 256 + 255) / 256, 256, 0, stream>>>(W[1], Wt2, 512, 256);
  k_transpose_cast<<<(256 * 32 + 255) / 256, 256, 0, stream>>>(W[2], Wt3, 256, 32);

  int gmM = (N + 127) / 128;

  // ---- layer 1: K=64, H=4, C=128, HC=512
  k_gemm_mfma<128, 128, 64, 64><<<dim3(gmM, 4), 256, 0, stream>>>(xbf, Wt1, bufH, N, 64, 512);
  k_attn_nd<<<N * 4, 64, 0, stream>>>(bufH, AS[0], AD[0], asrc, adst, N, 4, 128);
  k_watt<<<1, 64, 0, stream>>>(WE[0], AE[0], watt, 4, 128);
  k_edge_logit<4><<<(E + 255) / 256, 256, 0, stream>>>(src, dst, eattr, asrc, adst, watt, logitE, E);
  k_self_logit<4><<<(N + 255) / 256, 256, 0, stream>>>(loopAttr, watt, asrc, adst, lself, N);
  k_gather4<128, 8><<<N, 64, 0, stream>>>(rowStart, csrSrc, csrEid, logitE, lself, bufH,
                                          B[0], G[0], BT[0], RM[0], RV[0], bufA, N);

  // ---- layer 2: K=512, H=4, C=64, HC=256
  k_gemm_mfma<128, 128, 64, 64><<<dim3(gmM, 2), 256, 0, stream>>>(bufA, Wt2, bufH, N, 512, 256);
  k_attn_nd<<<N * 4, 64, 0, stream>>>(bufH, AS[1], AD[1], asrc, adst, N, 4, 64);
  k_watt<<<1, 64, 0, stream>>>(WE[1], AE[1], watt, 4, 64);
  k_edge_logit<4><<<(E + 255) / 256, 256, 0, stream>>>(src, dst, eattr, asrc, adst, watt, logitE, E);
  k_self_logit<4><<<(N + 255) / 256, 256, 0, stream>>>(loopAttr, watt, asrc, adst, lself, N);
  k_gather4<64, 4><<<N, 64, 0, stream>>>(rowStart, csrSrc, csrEid, logitE, lself, bufH,
                                         B[1], G[1], BT[1], RM[1], RV[1], bufA, N);

  // ---- layer 3: K=256, H=1, C=32
  k_gemm_mfma<128, 32, 32, 32><<<dim3(gmM, 1), 256, 0, stream>>>(bufA, Wt3, bufH, N, 256, 32);
  k_attn_nd<<<N, 64, 0, stream>>>(bufH, AS[2], AD[2], asrc, adst, N, 1, 32);
  k_watt<<<1, 64, 0, stream>>>(WE[2], AE[2], watt, 1, 32);
  k_edge_logit<1><<<(E + 255) / 256, 256, 0, stream>>>(src, dst, eattr, asrc, adst, watt, logitE, E);
  k_self_logit<1><<<(N + 255) / 256, 256, 0, stream>>>(loopAttr, watt, asrc, adst, lself, N);
  k_gather_L3<<<N, 64, 0, stream>>>(rowStart, csrSrc, csrEid, logitE, lself, bufH,
                                    B[2], G[2], BT[2], RM[2], RV[2], bufA, N);

  // ---- pooling + MLP
  k_pool<<<((size_t)N * 32 + 255) / 256, 256, 0, stream>>>(bufA, batch, meanSum, maxKey, count, N);
  k_mlp<<<NG, 64, 0, stream>>>(meanSum, maxKey, count, lw1, lb1, lw2, lb2, (float*)d_out, NG);
}

// Round 3
// 460.638 us; speedup vs baseline: 1.9247x; 1.2311x over previous
//
#include <hip/hip_runtime.h>
#include <math.h>

#define NEG_SLOPE 0.2f
#define BN_EPS 1e-5f

typedef __attribute__((ext_vector_type(8))) short bf16x8;
typedef __attribute__((ext_vector_type(4))) float f32x4;
typedef unsigned short u16;

static __device__ __forceinline__ float leaky(float v) { return v > 0.f ? v : NEG_SLOPE * v; }
static __device__ __forceinline__ float b2f(u16 b) { return __uint_as_float(((unsigned)b) << 16); }
static __device__ __forceinline__ u16 f2b(float f) {
  unsigned u = __float_as_uint(f);
  u += 0x7FFF + ((u >> 16) & 1);
  return (u16)(u >> 16);
}

// ---------------- setup ----------------
__global__ void k_deg(const int* __restrict__ dst, int* __restrict__ degInt, int E) {
  int e = blockIdx.x * blockDim.x + threadIdx.x;
  if (e < E) atomicAdd(&degInt[dst[e]], 1);
}

__global__ void k_scan(const int* __restrict__ degInt, int* __restrict__ rowStart, int n) {
  __shared__ int sums[1024];
  int tid = threadIdx.x;
  int per = (n + 1023) / 1024;
  int start = tid * per;
  int end = start + per; if (end > n) end = n;
  int s = 0;
  for (int i = start; i < end; i++) s += degInt[i];
  sums[tid] = s;
  __syncthreads();
  for (int off = 1; off < 1024; off <<= 1) {
    int v = (tid >= off) ? sums[tid - off] : 0;
    __syncthreads();
    sums[tid] += v;
    __syncthreads();
  }
  int base = (tid > 0) ? sums[tid - 1] : 0;
  for (int i = start; i < end; i++) { rowStart[i] = base; base += degInt[i]; }
  if (tid == 1023) rowStart[n] = sums[1023];
}

__global__ void k_fill_csr(const int* __restrict__ src, const int* __restrict__ dst,
                           const int* __restrict__ rowStart, int* __restrict__ cursor,
                           int* __restrict__ csrSrc, int* __restrict__ csrEid, int E) {
  int e = blockIdx.x * blockDim.x + threadIdx.x;
  if (e >= E) return;
  int d = dst[e];
  int pos = rowStart[d] + atomicAdd(&cursor[d], 1);
  csrSrc[pos] = src[e];
  csrEid[pos] = e;
}

// loopAttr[n][k] = mean of eattr over in-edges (no atomics; CSR gather)
__global__ void k_loop_gather(const int* __restrict__ rowStart, const int* __restrict__ csrEid,
                              const float* __restrict__ eattr, float* __restrict__ loopAttr, int Nn) {
  int i = blockIdx.x * blockDim.x + threadIdx.x;
  if (i >= Nn * 7) return;
  int n = i / 7, k = i % 7;
  int r0 = rowStart[n], r1 = rowStart[n + 1];
  float s = 0.f;
  for (int j = r0; j < r1; j++) s += eattr[csrEid[j] * 7 + k];
  loopAttr[i] = s / fmaxf((float)(r1 - r0), 1.0f);
}

// ---------------- casts ----------------
__global__ void k_cast_bf16(const float* __restrict__ in, u16* __restrict__ out, int n) {
  int i = blockIdx.x * blockDim.x + threadIdx.x;
  if (i < n) out[i] = f2b(in[i]);
}

__global__ void k_transpose_cast(const float* __restrict__ W, u16* __restrict__ Wt, int K, int N) {
  int i = blockIdx.x * blockDim.x + threadIdx.x;
  if (i >= K * N) return;
  int k = i / N, n = i % N;
  Wt[(size_t)n * K + k] = f2b(W[i]);
}

// ---------------- MFMA bf16 GEMM: C[M,N] = A[M,K] @ Bt[N,K]^T ----------------
template <int BM, int BN, int WM, int WN>
__global__ __launch_bounds__(256) void k_gemm_mfma(const u16* __restrict__ A,
                                                   const u16* __restrict__ Bt,
                                                   u16* __restrict__ Cout,
                                                   int M, int K, int N) {
  constexpr int BK = 64;
  constexpr int LDT = BK + 8;
  __shared__ u16 As[BM][LDT];
  __shared__ u16 Bs[BN][LDT];
  constexpr int NWN = BN / WN;
  constexpr int M_REP = WM / 16;
  constexpr int N_REP = WN / 16;
  int tid = threadIdx.x;
  int wid = tid >> 6, lane = tid & 63;
  int wr = wid / NWN, wc = wid % NWN;
  int bm = blockIdx.x * BM, bn = blockIdx.y * BN;
  int l15 = lane & 15, l4 = lane >> 4;

  f32x4 acc[M_REP][N_REP];
#pragma unroll
  for (int m = 0; m < M_REP; m++)
#pragma unroll
    for (int n = 0; n < N_REP; n++) acc[m][n] = (f32x4){0.f, 0.f, 0.f, 0.f};

  for (int k0 = 0; k0 < K; k0 += BK) {
    constexpr int CHA = BM * BK / 8;
#pragma unroll
    for (int ch0 = 0; ch0 < CHA; ch0 += 256) {
      int ch = ch0 + tid;
      int row = ch >> 3, cc = (ch & 7) * 8;
      int gr = bm + row;
      bf16x8 v = {};
      if (gr < M) v = *(const bf16x8*)(A + (size_t)gr * K + k0 + cc);
      *(bf16x8*)(&As[row][cc]) = v;
    }
    constexpr int CHB = BN * BK / 8;
#pragma unroll
    for (int ch0 = 0; ch0 < CHB; ch0 += 256) {
      int ch = ch0 + tid;
      int row = ch >> 3, cc = (ch & 7) * 8;
      int gr = bn + row;
      bf16x8 v = {};
      if (gr < N) v = *(const bf16x8*)(Bt + (size_t)gr * K + k0 + cc);
      *(bf16x8*)(&Bs[row][cc]) = v;
    }
    __syncthreads();
#pragma unroll
    for (int ks = 0; ks < BK; ks += 32) {
      bf16x8 af[M_REP], bfr[N_REP];
#pragma unroll
      for (int m = 0; m < M_REP; m++)
        af[m] = *(const bf16x8*)(&As[wr * WM + m * 16 + l15][ks + l4 * 8]);
#pragma unroll
      for (int n = 0; n < N_REP; n++)
        bfr[n] = *(const bf16x8*)(&Bs[wc * WN + n * 16 + l15][ks + l4 * 8]);
#pragma unroll
      for (int m = 0; m < M_REP; m++)
#pragma unroll
        for (int n = 0; n < N_REP; n++)
          acc[m][n] = __builtin_amdgcn_mfma_f32_16x16x32_bf16(af[m], bfr[n], acc[m][n], 0, 0, 0);
    }
    __syncthreads();
  }
#pragma unroll
  for (int m = 0; m < M_REP; m++) {
#pragma unroll
    for (int r = 0; r < 4; r++) {
      int grow = bm + wr * WM + m * 16 + l4 * 4 + r;
      if (grow >= M) continue;
#pragma unroll
      for (int n = 0; n < N_REP; n++) {
        int gcol = bn + wc * WN + n * 16 + l15;
        Cout[(size_t)grow * N + gcol] = f2b(acc[m][n][r]);
      }
    }
  }
}

// ---------------- per-(node,head) attention dots: 4 waves per block ----------------
__global__ __launch_bounds__(256) void k_attn_nd(const u16* __restrict__ hbuf,
                                                 const float* __restrict__ a_s, const float* __restrict__ a_d,
                                                 float* __restrict__ asrc, float* __restrict__ adst,
                                                 int total, int H, int C) {
  int idx = blockIdx.x * 4 + (threadIdx.x >> 6);
  if (idx >= total) return;
  int n = idx / H, h = idx % H;
  int lane = threadIdx.x & 63;
  float s1 = 0.f, s2 = 0.f;
  for (int c = lane; c < C; c += 64) {
    float v = b2f(hbuf[(size_t)n * H * C + h * C + c]);
    s1 += v * a_s[h * C + c];
    s2 += v * a_d[h * C + c];
  }
  for (int off = 32; off > 0; off >>= 1) { s1 += __shfl_xor(s1, off); s2 += __shfl_xor(s2, off); }
  if (lane == 0) { asrc[idx] = s1; adst[idx] = s2; }
}

__global__ void k_watt(const float* __restrict__ We, const float* __restrict__ a_e,
                       float* __restrict__ w_att, int H, int C) {
  int t = threadIdx.x;
  if (t >= 7 * H) return;
  int d = t / H, h = t % H;
  float s = 0.f;
  for (int c = 0; c < C; c++) s += We[(size_t)d * H * C + h * C + c] * a_e[h * C + c];
  w_att[d * H + h] = s;
}

template <int H>
__global__ void k_edge_logit(const int* __restrict__ src, const int* __restrict__ dst,
                             const float* __restrict__ eattr,
                             const float* __restrict__ asrc, const float* __restrict__ adst,
                             const float* __restrict__ w_att, float* __restrict__ logitE, int E) {
  int e = blockIdx.x * blockDim.x + threadIdx.x;
  if (e >= E) return;
  float ea[7];
#pragma unroll
  for (int d = 0; d < 7; d++) ea[d] = eattr[e * 7 + d];
  int s = src[e], dn = dst[e];
  if (H == 4) {
    f32x4 va = *(const f32x4*)(asrc + s * 4);
    f32x4 vd = *(const f32x4*)(adst + dn * 4);
    f32x4 o;
#pragma unroll
    for (int h = 0; h < 4; h++) {
      float ae = 0.f;
#pragma unroll
      for (int d = 0; d < 7; d++) ae += ea[d] * w_att[d * 4 + h];
      o[h] = leaky(va[h] + vd[h] + ae);
    }
    *(f32x4*)(logitE + e * 4) = o;
  } else {
    float ae = 0.f;
#pragma unroll
    for (int d = 0; d < 7; d++) ae += ea[d] * w_att[d];
    logitE[e] = leaky(asrc[s] + adst[dn] + ae);
  }
}

template <int H>
__global__ void k_self_logit(const float* __restrict__ loopAttr, const float* __restrict__ w_att,
                             const float* __restrict__ asrc, const float* __restrict__ adst,
                             float* __restrict__ lself, int Nn) {
  int n = blockIdx.x * blockDim.x + threadIdx.x;
  if (n >= Nn) return;
  float la[7];
#pragma unroll
  for (int d = 0; d < 7; d++) la[d] = loopAttr[n * 7 + d];
#pragma unroll
  for (int h = 0; h < H; h++) {
    float ae = 0.f;
#pragma unroll
    for (int d = 0; d < 7; d++) ae += la[d] * w_att[d * H + h];
    lself[n * H + h] = leaky(asrc[n * H + h] + adst[n * H + h] + ae);
  }
}

// ---------------- gather (H=4): 4 waves/block, one node per wave ----------------
template <int C, int CPL>
__global__ __launch_bounds__(256) void k_gather4(
    const int* __restrict__ rowStart, const int* __restrict__ csrSrc, const int* __restrict__ csrEid,
    const float* __restrict__ logitE, const float* __restrict__ lself,
    const u16* __restrict__ hbuf, const float* __restrict__ bias,
    const float* __restrict__ bng, const float* __restrict__ bnb,
    const float* __restrict__ bnrm, const float* __restrict__ bnrv,
    u16* __restrict__ outbuf, int Nn) {
  constexpr int HC = 4 * C;
  typedef __attribute__((ext_vector_type(CPL))) unsigned short u16v;
  int n = blockIdx.x * 4 + (threadIdx.x >> 6);
  if (n >= Nn) return;
  int lane = threadIdx.x & 63;
  int r0 = rowStart[n], r1 = rowStart[n + 1];
  int hs = lane >> 4;

  float ls[4];
#pragma unroll
  for (int h = 0; h < 4; h++) ls[h] = lself[n * 4 + h];

  const f32x4* L4 = (const f32x4*)logitE;

  float m[4];
#pragma unroll
  for (int h = 0; h < 4; h++) m[h] = -1e30f;
  for (int j = r0 + lane; j < r1; j += 64) {
    f32x4 lv = L4[csrEid[j]];
#pragma unroll
    for (int h = 0; h < 4; h++) m[h] = fmaxf(m[h], lv[h]);
  }
#pragma unroll
  for (int h = 0; h < 4; h++) {
    float v = m[h];
    for (int off = 32; off > 0; off >>= 1) v = fmaxf(v, __shfl_xor(v, off));
    m[h] = fmaxf(v, ls[h]);
  }
  float den[4];
#pragma unroll
  for (int h = 0; h < 4; h++) den[h] = 0.f;
  for (int j = r0 + lane; j < r1; j += 64) {
    f32x4 lv = L4[csrEid[j]];
#pragma unroll
    for (int h = 0; h < 4; h++) den[h] += __expf(lv[h] - m[h]);
  }
#pragma unroll
  for (int h = 0; h < 4; h++) {
    float v = den[h];
    for (int off = 32; off > 0; off >>= 1) v += __shfl_xor(v, off);
    den[h] = v + __expf(ls[h] - m[h]);
  }
  float mh = hs == 0 ? m[0] : hs == 1 ? m[1] : hs == 2 ? m[2] : m[3];
  float dh = hs == 0 ? den[0] : hs == 1 ? den[1] : hs == 2 ? den[2] : den[3];
  float lsh = hs == 0 ? ls[0] : hs == 1 ? ls[1] : hs == 2 ? ls[2] : ls[3];

  // phase B: 4 edges in flight
  float acc[CPL];
#pragma unroll
  for (int j = 0; j < CPL; j++) acc[j] = 0.f;
  int j = r0;
  for (; j + 3 < r1; j += 4) {
    int e0 = csrEid[j],     s0 = csrSrc[j];
    int e1 = csrEid[j + 1], s1 = csrSrc[j + 1];
    int e2 = csrEid[j + 2], s2 = csrSrc[j + 2];
    int e3 = csrEid[j + 3], s3 = csrSrc[j + 3];
    float lg0 = logitE[e0 * 4 + hs], lg1 = logitE[e1 * 4 + hs];
    float lg2 = logitE[e2 * 4 + hs], lg3 = logitE[e3 * 4 + hs];
    u16v h0 = *(const u16v*)(hbuf + (size_t)s0 * HC + lane * CPL);
    u16v h1 = *(const u16v*)(hbuf + (size_t)s1 * HC + lane * CPL);
    u16v h2 = *(const u16v*)(hbuf + (size_t)s2 * HC + lane * CPL);
    u16v h3 = *(const u16v*)(hbuf + (size_t)s3 * HC + lane * CPL);
    float p0 = __expf(lg0 - mh), p1 = __expf(lg1 - mh);
    float p2 = __expf(lg2 - mh), p3 = __expf(lg3 - mh);
#pragma unroll
    for (int jj = 0; jj < CPL; jj++)
      acc[jj] += p0 * b2f(h0[jj]) + p1 * b2f(h1[jj]) + p2 * b2f(h2[jj]) + p3 * b2f(h3[jj]);
  }
  for (; j < r1; j++) {
    int e0 = csrEid[j], s0 = csrSrc[j];
    float p0 = __expf(logitE[e0 * 4 + hs] - mh);
    u16v h0 = *(const u16v*)(hbuf + (size_t)s0 * HC + lane * CPL);
#pragma unroll
    for (int jj = 0; jj < CPL; jj++) acc[jj] += p0 * b2f(h0[jj]);
  }
  {
    float ps = __expf(lsh - mh);
    u16v hN = *(const u16v*)(hbuf + (size_t)n * HC + lane * CPL);
#pragma unroll
    for (int jj = 0; jj < CPL; jj++) acc[jj] += ps * b2f(hN[jj]);
  }
  u16v ov;
#pragma unroll
  for (int jj = 0; jj < CPL; jj++) {
    int c = lane * CPL + jj;
    float v = acc[jj] / dh + bias[c];
    v = (v - bnrm[c]) * (bng[c] * rsqrtf(bnrv[c] + BN_EPS)) + bnb[c];
    ov[jj] = f2b(fmaxf(v, 0.f));
  }
  *(u16v*)(outbuf + (size_t)n * HC + lane * CPL) = ov;
}

// ---------------- gather (H=1, C=32): 4 waves/block ----------------
__global__ __launch_bounds__(256) void k_gather_L3(
    const int* __restrict__ rowStart, const int* __restrict__ csrSrc, const int* __restrict__ csrEid,
    const float* __restrict__ logitE, const float* __restrict__ lself,
    const u16* __restrict__ hbuf, const float* __restrict__ bias,
    const float* __restrict__ bng, const float* __restrict__ bnb,
    const float* __restrict__ bnrm, const float* __restrict__ bnrv,
    u16* __restrict__ outbuf, int Nn) {
  int n = blockIdx.x * 4 + (threadIdx.x >> 6);
  if (n >= Nn) return;
  int lane = threadIdx.x & 63;
  int cl = lane & 31, half = lane >> 5;
  int r0 = rowStart[n], r1 = rowStart[n + 1];
  float ls = lself[n];

  float m = -1e30f;
  for (int j = r0 + lane; j < r1; j += 64) m = fmaxf(m, logitE[csrEid[j]]);
  for (int off = 32; off > 0; off >>= 1) m = fmaxf(m, __shfl_xor(m, off));
  m = fmaxf(m, ls);
  float den = 0.f;
  for (int j = r0 + lane; j < r1; j += 64) den += __expf(logitE[csrEid[j]] - m);
  for (int off = 32; off > 0; off >>= 1) den += __shfl_xor(den, off);
  den += __expf(ls - m);

  float acc = 0.f;
  for (int j = r0 + half; j < r1; j += 2) {
    int eid = csrEid[j], s = csrSrc[j];
    float p = __expf(logitE[eid] - m);
    acc += p * b2f(hbuf[(size_t)s * 32 + cl]);
  }
  if (half == 0) acc += __expf(ls - m) * b2f(hbuf[(size_t)n * 32 + cl]);
  acc += __shfl_xor(acc, 32);
  if (half == 0) {
    float v = acc / den + bias[cl];
    v = (v - bnrm[cl]) * (bng[cl] * rsqrtf(bnrv[cl] + BN_EPS)) + bnb[cl];
    outbuf[(size_t)n * 32 + cl] = f2b(fmaxf(v, 0.f));
  }
}

// ---------------- pooling ----------------
__global__ void k_pool(const u16* __restrict__ h3, const int* __restrict__ batch,
                       float* __restrict__ meanSum, unsigned int* __restrict__ maxKey,
                       int* __restrict__ count, int Nn) {
  int i = blockIdx.x * blockDim.x + threadIdx.x;
  if (i >= Nn * 32) return;
  int n = i >> 5, c = i & 31;
  int g = batch[n];
  float v = b2f(h3[i]);
  atomicAdd(&meanSum[g * 32 + c], v);
  atomicMax(&maxKey[g * 32 + c], __float_as_uint(v));
  if (c == 0) atomicAdd(&count[g], 1);
}

__global__ __launch_bounds__(64) void k_mlp(const float* __restrict__ meanSum,
                                            const unsigned int* __restrict__ maxKey,
                                            const int* __restrict__ count,
                                            const float* __restrict__ lw1, const float* __restrict__ lb1,
                                            const float* __restrict__ lw2, const float* __restrict__ lb2,
                                            float* __restrict__ out, int NG) {
  int g = blockIdx.x;
  int t = threadIdx.x;
  __shared__ float z[64];
  __shared__ float z1[32];
  float cnt = fmaxf((float)count[g], 1.0f);
  if (t < 32) z[t] = meanSum[g * 32 + t] / cnt;
  else        z[t] = __uint_as_float(maxKey[g * 32 + (t - 32)]);
  __syncthreads();
  if (t < 32) {
    float s = lb1[t];
    for (int k = 0; k < 64; k++) s += z[k] * lw1[k * 32 + t];
    z1[t] = fmaxf(s, 0.f);
  }
  __syncthreads();
  if (t == 0) {
    float s = lb2[0];
    for (int j = 0; j < 32; j++) s += z1[j] * lw2[j];
    out[g] = 1.f / (1.f + expf(-s));
  }
}

// ---------------- driver ----------------
extern "C" void kernel_launch(void* const* d_in, const int* in_sizes, int n_in,
                              void* d_out, int out_size, void* d_ws, size_t ws_size,
                              hipStream_t stream) {
  const float* x     = (const float*)d_in[0];
  const int*   eidx  = (const int*)d_in[1];
  const float* eattr = (const float*)d_in[2];
  const int*   batch = (const int*)d_in[3];
  int N = in_sizes[0] / 64;
  int E = in_sizes[1] / 2;
  int NG = out_size;
  const int* src = eidx;
  const int* dst = eidx + E;

  const float* W[3]  = {(const float*)d_in[4],  (const float*)d_in[14], (const float*)d_in[24]};
  const float* AS[3] = {(const float*)d_in[5],  (const float*)d_in[15], (const float*)d_in[25]};
  const float* AD[3] = {(const float*)d_in[6],  (const float*)d_in[16], (const float*)d_in[26]};
  const float* WE[3] = {(const float*)d_in[7],  (const float*)d_in[17], (const float*)d_in[27]};
  const float* AE[3] = {(const float*)d_in[8],  (const float*)d_in[18], (const float*)d_in[28]};
  const float* B[3]  = {(const float*)d_in[9],  (const float*)d_in[19], (const float*)d_in[29]};
  const float* G[3]  = {(const float*)d_in[10], (const float*)d_in[20], (const float*)d_in[30]};
  const float* BT[3] = {(const float*)d_in[11], (const float*)d_in[21], (const float*)d_in[31]};
  const float* RM[3] = {(const float*)d_in[12], (const float*)d_in[22], (const float*)d_in[32]};
  const float* RV[3] = {(const float*)d_in[13], (const float*)d_in[23], (const float*)d_in[33]};
  const float* lw1 = (const float*)d_in[34];
  const float* lb1 = (const float*)d_in[35];
  const float* lw2 = (const float*)d_in[36];
  const float* lb2 = (const float*)d_in[37];

  char* wp = (char*)d_ws;
  auto alloc = [&](size_t bytes) -> void* {
    void* p = (void*)wp;
    wp += (bytes + 255) & ~(size_t)255;
    return p;
  };
  u16*   xbf      = (u16*)alloc((size_t)N * 64 * 2);
  u16*   bufH     = (u16*)alloc((size_t)N * 512 * 2);
  u16*   bufA     = (u16*)alloc((size_t)N * 512 * 2);
  u16*   Wt1      = (u16*)alloc((size_t)512 * 64 * 2);
  u16*   Wt2      = (u16*)alloc((size_t)256 * 512 * 2);
  u16*   Wt3      = (u16*)alloc((size_t)32 * 256 * 2);
  int*   degInt   = (int*)alloc((size_t)N * 4);
  int*   cursor   = (int*)alloc((size_t)N * 4);
  int*   rowStart = (int*)alloc((size_t)(N + 1) * 4);
  float* loopAttr = (float*)alloc((size_t)N * 7 * 4);
  int*   csrSrc   = (int*)alloc((size_t)E * 4);
  int*   csrEid   = (int*)alloc((size_t)E * 4);
  float* logitE   = (float*)alloc((size_t)E * 4 * 4);
  float* asrc     = (float*)alloc((size_t)N * 4 * 4);
  float* adst     = (float*)alloc((size_t)N * 4 * 4);
  float* lself    = (float*)alloc((size_t)N * 4 * 4);
  float* watt     = (float*)alloc(32 * 4);
  float* meanSum  = (float*)alloc((size_t)NG * 32 * 4);
  unsigned int* maxKey = (unsigned int*)alloc((size_t)NG * 32 * 4);
  int*   count    = (int*)alloc((size_t)NG * 4);

  hipMemsetAsync(degInt, 0, (size_t)N * 4, stream);
  hipMemsetAsync(cursor, 0, (size_t)N * 4, stream);
  hipMemsetAsync(meanSum, 0, (size_t)NG * 32 * 4, stream);
  hipMemsetAsync(maxKey, 0, (size_t)NG * 32 * 4, stream);
  hipMemsetAsync(count, 0, (size_t)NG * 4, stream);

  // setup
  k_deg<<<(E + 255) / 256, 256, 0, stream>>>(dst, degInt, E);
  k_scan<<<1, 1024, 0, stream>>>(degInt, rowStart, N);
  k_fill_csr<<<(E + 255) / 256, 256, 0, stream>>>(src, dst, rowStart, cursor, csrSrc, csrEid, E);
  k_loop_gather<<<(N * 7 + 255) / 256, 256, 0, stream>>>(rowStart, csrEid, eattr, loopAttr, N);
  k_cast_bf16<<<(N * 64 + 255) / 256, 256, 0, stream>>>(x, xbf, N * 64);
  k_transpose_cast<<<(64 * 512 + 255) / 256, 256, 0, stream>>>(W[0], Wt1, 64, 512);
  k_transpose_cast<<<(512 * 256 + 255) / 256, 256, 0, stream>>>(W[1], Wt2, 512, 256);
  k_transpose_cast<<<(256 * 32 + 255) / 256, 256, 0, stream>>>(W[2], Wt3, 256, 32);

  int gmM = (N + 127) / 128;
  int nb4 = (N + 3) / 4;

  // ---- layer 1: K=64, H=4, C=128, HC=512
  k_gemm_mfma<128, 128, 64, 64><<<dim3(gmM, 4), 256, 0, stream>>>(xbf, Wt1, bufH, N, 64, 512);
  k_attn_nd<<<(N * 4 + 3) / 4, 256, 0, stream>>>(bufH, AS[0], AD[0], asrc, adst, N * 4, 4, 128);
  k_watt<<<1, 64, 0, stream>>>(WE[0], AE[0], watt, 4, 128);
  k_edge_logit<4><<<(E + 255) / 256, 256, 0, stream>>>(src, dst, eattr, asrc, adst, watt, logitE, E);
  k_self_logit<4><<<(N + 255) / 256, 256, 0, stream>>>(loopAttr, watt, asrc, adst, lself, N);
  k_gather4<128, 8><<<nb4, 256, 0, stream>>>(rowStart, csrSrc, csrEid, logitE, lself, bufH,
                                             B[0], G[0], BT[0], RM[0], RV[0], bufA, N);

  // ---- layer 2: K=512, H=4, C=64, HC=256
  k_gemm_mfma<128, 128, 64, 64><<<dim3(gmM, 2), 256, 0, stream>>>(bufA, Wt2, bufH, N, 512, 256);
  k_attn_nd<<<(N * 4 + 3) / 4, 256, 0, stream>>>(bufH, AS[1], AD[1], asrc, adst, N * 4, 4, 64);
  k_watt<<<1, 64, 0, stream>>>(WE[1], AE[1], watt, 4, 64);
  k_edge_logit<4><<<(E + 255) / 256, 256, 0, stream>>>(src, dst, eattr, asrc, adst, watt, logitE, E);
  k_self_logit<4><<<(N + 255) / 256, 256, 0, stream>>>(loopAttr, watt, asrc, adst, lself, N);
  k_gather4<64, 4><<<nb4, 256, 0, stream>>>(rowStart, csrSrc, csrEid, logitE, lself, bufH,
                                            B[1], G[1], BT[1], RM[1], RV[1], bufA, N);

  // ---- layer 3: K=256, H=1, C=32
  k_gemm_mfma<128, 32, 32, 32><<<dim3(gmM, 1), 256, 0, stream>>>(bufA, Wt3, bufH, N, 256, 32);
  k_attn_nd<<<(N + 3) / 4, 256, 0, stream>>>(bufH, AS[2], AD[2], asrc, adst, N, 1, 32);
  k_watt<<<1, 64, 0, stream>>>(WE[2], AE[2], watt, 1, 32);
  k_edge_logit<1><<<(E + 255) / 256, 256, 0, stream>>>(src, dst, eattr, asrc, adst, watt, logitE, E);
  k_self_logit<1><<<(N + 255) / 256, 256, 0, stream>>>(loopAttr, watt, asrc, adst, lself, N);
  k_gather_L3<<<nb4, 256, 0, stream>>>(rowStart, csrSrc, csrEid, logitE, lself, bufH,
                                       B[2], G[2], BT[2], RM[2], RV[2], bufA, N);

  // ---- pooling + MLP
  k_pool<<<((size_t)N * 32 + 255) / 256, 256, 0, stream>>>(bufA, batch, meanSum, maxKey, count, N);
  k_mlp<<<NG, 64, 0, stream>>>(meanSum, maxKey, count, lw1, lb1, lw2, lb2, (float*)d_out, NG);
}

// Round 4
// 355.034 us; speedup vs baseline: 2.4972x; 1.2974x over previous
//
#include <hip/hip_runtime.h>
#include <math.h>

#define NEG_SLOPE 0.2f
#define BN_EPS 1e-5f

typedef __attribute__((ext_vector_type(8))) short bf16x8;
typedef __attribute__((ext_vector_type(4))) float f32x4;
typedef unsigned short u16;

static __device__ __forceinline__ float leaky(float v) { return v > 0.f ? v : NEG_SLOPE * v; }
static __device__ __forceinline__ float b2f(u16 b) { return __uint_as_float(((unsigned)b) << 16); }
static __device__ __forceinline__ u16 f2b(float f) {
  unsigned u = __float_as_uint(f);
  u += 0x7FFF + ((u >> 16) & 1);
  return (u16)(u >> 16);
}

// ---------------- setup ----------------
__global__ void k_deg(const int* __restrict__ dst, int* __restrict__ degInt, int E) {
  int e = blockIdx.x * blockDim.x + threadIdx.x;
  if (e < E) atomicAdd(&degInt[dst[e]], 1);
}

__global__ void k_scan(const int* __restrict__ degInt, int* __restrict__ rowStart, int n) {
  __shared__ int sums[1024];
  int tid = threadIdx.x;
  int per = (n + 1023) / 1024;
  int start = tid * per;
  int end = start + per; if (end > n) end = n;
  int s = 0;
  for (int i = start; i < end; i++) s += degInt[i];
  sums[tid] = s;
  __syncthreads();
  for (int off = 1; off < 1024; off <<= 1) {
    int v = (tid >= off) ? sums[tid - off] : 0;
    __syncthreads();
    sums[tid] += v;
    __syncthreads();
  }
  int base = (tid > 0) ? sums[tid - 1] : 0;
  for (int i = start; i < end; i++) { rowStart[i] = base; base += degInt[i]; }
  if (tid == 1023) rowStart[n] = sums[1023];
}

__global__ void k_fill_csr(const int* __restrict__ src, const int* __restrict__ dst,
                           const int* __restrict__ rowStart, int* __restrict__ cursor,
                           int* __restrict__ csrSrc, int* __restrict__ csrEid, int E) {
  int e = blockIdx.x * blockDim.x + threadIdx.x;
  if (e >= E) return;
  int d = dst[e];
  int pos = rowStart[d] + atomicAdd(&cursor[d], 1);
  csrSrc[pos] = src[e];
  csrEid[pos] = e;
}

// loopAttr[n][k] = mean of eattr over in-edges (no atomics; CSR gather)
__global__ void k_loop_gather(const int* __restrict__ rowStart, const int* __restrict__ csrEid,
                              const float* __restrict__ eattr, float* __restrict__ loopAttr, int Nn) {
  int i = blockIdx.x * blockDim.x + threadIdx.x;
  if (i >= Nn * 7) return;
  int n = i / 7, k = i % 7;
  int r0 = rowStart[n], r1 = rowStart[n + 1];
  float s = 0.f;
  for (int j = r0; j < r1; j++) s += eattr[csrEid[j] * 7 + k];
  loopAttr[i] = s / fmaxf((float)(r1 - r0), 1.0f);
}

// ---------------- casts ----------------
__global__ void k_cast_bf16(const float* __restrict__ in, u16* __restrict__ out, int n) {
  int i = blockIdx.x * blockDim.x + threadIdx.x;
  if (i < n) out[i] = f2b(in[i]);
}

__global__ void k_transpose_cast(const float* __restrict__ W, u16* __restrict__ Wt, int K, int N) {
  int i = blockIdx.x * blockDim.x + threadIdx.x;
  if (i >= K * N) return;
  int k = i / N, n = i % N;
  Wt[(size_t)n * K + k] = f2b(W[i]);
}

// ---------------- MFMA bf16 GEMM: C[M,N] = A[M,K] @ Bt[N,K]^T ----------------
template <int BM, int BN, int WM, int WN>
__global__ __launch_bounds__(256) void k_gemm_mfma(const u16* __restrict__ A,
                                                   const u16* __restrict__ Bt,
                                                   u16* __restrict__ Cout,
                                                   int M, int K, int N) {
  constexpr int BK = 64;
  constexpr int LDT = BK + 8;
  __shared__ u16 As[BM][LDT];
  __shared__ u16 Bs[BN][LDT];
  constexpr int NWN = BN / WN;
  constexpr int M_REP = WM / 16;
  constexpr int N_REP = WN / 16;
  int tid = threadIdx.x;
  int wid = tid >> 6, lane = tid & 63;
  int wr = wid / NWN, wc = wid % NWN;
  int bm = blockIdx.x * BM, bn = blockIdx.y * BN;
  int l15 = lane & 15, l4 = lane >> 4;

  f32x4 acc[M_REP][N_REP];
#pragma unroll
  for (int m = 0; m < M_REP; m++)
#pragma unroll
    for (int n = 0; n < N_REP; n++) acc[m][n] = (f32x4){0.f, 0.f, 0.f, 0.f};

  for (int k0 = 0; k0 < K; k0 += BK) {
    constexpr int CHA = BM * BK / 8;
#pragma unroll
    for (int ch0 = 0; ch0 < CHA; ch0 += 256) {
      int ch = ch0 + tid;
      int row = ch >> 3, cc = (ch & 7) * 8;
      int gr = bm + row;
      bf16x8 v = {};
      if (gr < M) v = *(const bf16x8*)(A + (size_t)gr * K + k0 + cc);
      *(bf16x8*)(&As[row][cc]) = v;
    }
    constexpr int CHB = BN * BK / 8;
#pragma unroll
    for (int ch0 = 0; ch0 < CHB; ch0 += 256) {
      int ch = ch0 + tid;
      int row = ch >> 3, cc = (ch & 7) * 8;
      int gr = bn + row;
      bf16x8 v = {};
      if (gr < N) v = *(const bf16x8*)(Bt + (size_t)gr * K + k0 + cc);
      *(bf16x8*)(&Bs[row][cc]) = v;
    }
    __syncthreads();
#pragma unroll
    for (int ks = 0; ks < BK; ks += 32) {
      bf16x8 af[M_REP], bfr[N_REP];
#pragma unroll
      for (int m = 0; m < M_REP; m++)
        af[m] = *(const bf16x8*)(&As[wr * WM + m * 16 + l15][ks + l4 * 8]);
#pragma unroll
      for (int n = 0; n < N_REP; n++)
        bfr[n] = *(const bf16x8*)(&Bs[wc * WN + n * 16 + l15][ks + l4 * 8]);
#pragma unroll
      for (int m = 0; m < M_REP; m++)
#pragma unroll
        for (int n = 0; n < N_REP; n++)
          acc[m][n] = __builtin_amdgcn_mfma_f32_16x16x32_bf16(af[m], bfr[n], acc[m][n], 0, 0, 0);
    }
    __syncthreads();
  }
#pragma unroll
  for (int m = 0; m < M_REP; m++) {
#pragma unroll
    for (int r = 0; r < 4; r++) {
      int grow = bm + wr * WM + m * 16 + l4 * 4 + r;
      if (grow >= M) continue;
#pragma unroll
      for (int n = 0; n < N_REP; n++) {
        int gcol = bn + wc * WN + n * 16 + l15;
        Cout[(size_t)grow * N + gcol] = f2b(acc[m][n][r]);
      }
    }
  }
}

// ---------------- per-(node,head) attention dots: 4 waves per block ----------------
__global__ __launch_bounds__(256) void k_attn_nd(const u16* __restrict__ hbuf,
                                                 const float* __restrict__ a_s, const float* __restrict__ a_d,
                                                 float* __restrict__ asrc, float* __restrict__ adst,
                                                 int total, int H, int C) {
  int idx = blockIdx.x * 4 + (threadIdx.x >> 6);
  if (idx >= total) return;
  int n = idx / H, h = idx % H;
  int lane = threadIdx.x & 63;
  float s1 = 0.f, s2 = 0.f;
  for (int c = lane; c < C; c += 64) {
    float v = b2f(hbuf[(size_t)n * H * C + h * C + c]);
    s1 += v * a_s[h * C + c];
    s2 += v * a_d[h * C + c];
  }
  for (int off = 32; off > 0; off >>= 1) { s1 += __shfl_xor(s1, off); s2 += __shfl_xor(s2, off); }
  if (lane == 0) { asrc[idx] = s1; adst[idx] = s2; }
}

__global__ void k_watt(const float* __restrict__ We, const float* __restrict__ a_e,
                       float* __restrict__ w_att, int H, int C) {
  int t = threadIdx.x;
  if (t >= 7 * H) return;
  int d = t / H, h = t % H;
  float s = 0.f;
  for (int c = 0; c < C; c++) s += We[(size_t)d * H * C + h * C + c] * a_e[h * C + c];
  w_att[d * H + h] = s;
}

template <int H>
__global__ void k_edge_logit(const int* __restrict__ src, const int* __restrict__ dst,
                             const float* __restrict__ eattr,
                             const float* __restrict__ asrc, const float* __restrict__ adst,
                             const float* __restrict__ w_att, float* __restrict__ logitE, int E) {
  int e = blockIdx.x * blockDim.x + threadIdx.x;
  if (e >= E) return;
  float ea[7];
#pragma unroll
  for (int d = 0; d < 7; d++) ea[d] = eattr[e * 7 + d];
  int s = src[e], dn = dst[e];
  if (H == 4) {
    f32x4 va = *(const f32x4*)(asrc + s * 4);
    f32x4 vd = *(const f32x4*)(adst + dn * 4);
    f32x4 o;
#pragma unroll
    for (int h = 0; h < 4; h++) {
      float ae = 0.f;
#pragma unroll
      for (int d = 0; d < 7; d++) ae += ea[d] * w_att[d * 4 + h];
      o[h] = leaky(va[h] + vd[h] + ae);
    }
    *(f32x4*)(logitE + e * 4) = o;
  } else {
    float ae = 0.f;
#pragma unroll
    for (int d = 0; d < 7; d++) ae += ea[d] * w_att[d];
    logitE[e] = leaky(asrc[s] + adst[dn] + ae);
  }
}

template <int H>
__global__ void k_self_logit(const float* __restrict__ loopAttr, const float* __restrict__ w_att,
                             const float* __restrict__ asrc, const float* __restrict__ adst,
                             float* __restrict__ lself, int Nn) {
  int n = blockIdx.x * blockDim.x + threadIdx.x;
  if (n >= Nn) return;
  float la[7];
#pragma unroll
  for (int d = 0; d < 7; d++) la[d] = loopAttr[n * 7 + d];
#pragma unroll
  for (int h = 0; h < H; h++) {
    float ae = 0.f;
#pragma unroll
    for (int d = 0; d < 7; d++) ae += la[d] * w_att[d * H + h];
    lself[n * H + h] = leaky(asrc[n * H + h] + adst[n * H + h] + ae);
  }
}

// ---------------- gather (H=4): 4 waves/block, one node per wave ----------------
template <int C, int CPL>
__global__ __launch_bounds__(256) void k_gather4(
    const int* __restrict__ rowStart, const int* __restrict__ csrSrc, const int* __restrict__ csrEid,
    const float* __restrict__ logitE, const float* __restrict__ lself,
    const u16* __restrict__ hbuf, const float* __restrict__ bias,
    const float* __restrict__ bng, const float* __restrict__ bnb,
    const float* __restrict__ bnrm, const float* __restrict__ bnrv,
    u16* __restrict__ outbuf, int Nn) {
  constexpr int HC = 4 * C;
  typedef __attribute__((ext_vector_type(CPL))) unsigned short u16v;
  int n = blockIdx.x * 4 + (threadIdx.x >> 6);
  if (n >= Nn) return;
  int lane = threadIdx.x & 63;
  int r0 = rowStart[n], r1 = rowStart[n + 1];
  int hs = lane >> 4;

  float ls[4];
#pragma unroll
  for (int h = 0; h < 4; h++) ls[h] = lself[n * 4 + h];

  const f32x4* L4 = (const f32x4*)logitE;

  float m[4];
#pragma unroll
  for (int h = 0; h < 4; h++) m[h] = -1e30f;
  for (int j = r0 + lane; j < r1; j += 64) {
    f32x4 lv = L4[csrEid[j]];
#pragma unroll
    for (int h = 0; h < 4; h++) m[h] = fmaxf(m[h], lv[h]);
  }
#pragma unroll
  for (int h = 0; h < 4; h++) {
    float v = m[h];
    for (int off = 32; off > 0; off >>= 1) v = fmaxf(v, __shfl_xor(v, off));
    m[h] = fmaxf(v, ls[h]);
  }
  float den[4];
#pragma unroll
  for (int h = 0; h < 4; h++) den[h] = 0.f;
  for (int j = r0 + lane; j < r1; j += 64) {
    f32x4 lv = L4[csrEid[j]];
#pragma unroll
    for (int h = 0; h < 4; h++) den[h] += __expf(lv[h] - m[h]);
  }
#pragma unroll
  for (int h = 0; h < 4; h++) {
    float v = den[h];
    for (int off = 32; off > 0; off >>= 1) v += __shfl_xor(v, off);
    den[h] = v + __expf(ls[h] - m[h]);
  }
  float mh = hs == 0 ? m[0] : hs == 1 ? m[1] : hs == 2 ? m[2] : m[3];
  float dh = hs == 0 ? den[0] : hs == 1 ? den[1] : hs == 2 ? den[2] : den[3];
  float lsh = hs == 0 ? ls[0] : hs == 1 ? ls[1] : hs == 2 ? ls[2] : ls[3];

  // phase B: 4 edges in flight
  float acc[CPL];
#pragma unroll
  for (int j = 0; j < CPL; j++) acc[j] = 0.f;
  int j = r0;
  for (; j + 3 < r1; j += 4) {
    int e0 = csrEid[j],     s0 = csrSrc[j];
    int e1 = csrEid[j + 1], s1 = csrSrc[j + 1];
    int e2 = csrEid[j + 2], s2 = csrSrc[j + 2];
    int e3 = csrEid[j + 3], s3 = csrSrc[j + 3];
    float lg0 = logitE[e0 * 4 + hs], lg1 = logitE[e1 * 4 + hs];
    float lg2 = logitE[e2 * 4 + hs], lg3 = logitE[e3 * 4 + hs];
    u16v h0 = *(const u16v*)(hbuf + (size_t)s0 * HC + lane * CPL);
    u16v h1 = *(const u16v*)(hbuf + (size_t)s1 * HC + lane * CPL);
    u16v h2 = *(const u16v*)(hbuf + (size_t)s2 * HC + lane * CPL);
    u16v h3 = *(const u16v*)(hbuf + (size_t)s3 * HC + lane * CPL);
    float p0 = __expf(lg0 - mh), p1 = __expf(lg1 - mh);
    float p2 = __expf(lg2 - mh), p3 = __expf(lg3 - mh);
#pragma unroll
    for (int jj = 0; jj < CPL; jj++)
      acc[jj] += p0 * b2f(h0[jj]) + p1 * b2f(h1[jj]) + p2 * b2f(h2[jj]) + p3 * b2f(h3[jj]);
  }
  for (; j < r1; j++) {
    int e0 = csrEid[j], s0 = csrSrc[j];
    float p0 = __expf(logitE[e0 * 4 + hs] - mh);
    u16v h0 = *(const u16v*)(hbuf + (size_t)s0 * HC + lane * CPL);
#pragma unroll
    for (int jj = 0; jj < CPL; jj++) acc[jj] += p0 * b2f(h0[jj]);
  }
  {
    float ps = __expf(lsh - mh);
    u16v hN = *(const u16v*)(hbuf + (size_t)n * HC + lane * CPL);
#pragma unroll
    for (int jj = 0; jj < CPL; jj++) acc[jj] += ps * b2f(hN[jj]);
  }
  u16v ov;
#pragma unroll
  for (int jj = 0; jj < CPL; jj++) {
    int c = lane * CPL + jj;
    float v = acc[jj] / dh + bias[c];
    v = (v - bnrm[c]) * (bng[c] * rsqrtf(bnrv[c] + BN_EPS)) + bnb[c];
    ov[jj] = f2b(fmaxf(v, 0.f));
  }
  *(u16v*)(outbuf + (size_t)n * HC + lane * CPL) = ov;
}

// ---------------- gather (H=1, C=32): 4 waves/block ----------------
__global__ __launch_bounds__(256) void k_gather_L3(
    const int* __restrict__ rowStart, const int* __restrict__ csrSrc, const int* __restrict__ csrEid,
    const float* __restrict__ logitE, const float* __restrict__ lself,
    const u16* __restrict__ hbuf, const float* __restrict__ bias,
    const float* __restrict__ bng, const float* __restrict__ bnb,
    const float* __restrict__ bnrm, const float* __restrict__ bnrv,
    u16* __restrict__ outbuf, int Nn) {
  int n = blockIdx.x * 4 + (threadIdx.x >> 6);
  if (n >= Nn) return;
  int lane = threadIdx.x & 63;
  int cl = lane & 31, half = lane >> 5;
  int r0 = rowStart[n], r1 = rowStart[n + 1];
  float ls = lself[n];

  float m = -1e30f;
  for (int j = r0 + lane; j < r1; j += 64) m = fmaxf(m, logitE[csrEid[j]]);
  for (int off = 32; off > 0; off >>= 1) m = fmaxf(m, __shfl_xor(m, off));
  m = fmaxf(m, ls);
  float den = 0.f;
  for (int j = r0 + lane; j < r1; j += 64) den += __expf(logitE[csrEid[j]] - m);
  for (int off = 32; off > 0; off >>= 1) den += __shfl_xor(den, off);
  den += __expf(ls - m);

  float acc = 0.f;
  for (int j = r0 + half; j < r1; j += 2) {
    int eid = csrEid[j], s = csrSrc[j];
    float p = __expf(logitE[eid] - m);
    acc += p * b2f(hbuf[(size_t)s * 32 + cl]);
  }
  if (half == 0) acc += __expf(ls - m) * b2f(hbuf[(size_t)n * 32 + cl]);
  acc += __shfl_xor(acc, 32);
  if (half == 0) {
    float v = acc / den + bias[cl];
    v = (v - bnrm[cl]) * (bng[cl] * rsqrtf(bnrv[cl] + BN_EPS)) + bnb[cl];
    outbuf[(size_t)n * 32 + cl] = f2b(fmaxf(v, 0.f));
  }
}

// ---------------- fused pooling + MLP (batch is SORTED -> segmented reduce, no atomics) ----------------
__global__ __launch_bounds__(256) void k_pool_mlp(
    const u16* __restrict__ h3, const int* __restrict__ batch, int Nn,
    const float* __restrict__ lw1, const float* __restrict__ lb1,
    const float* __restrict__ lw2, const float* __restrict__ lb2,
    float* __restrict__ out) {
  int g = blockIdx.x;
  int tid = threadIdx.x;
  __shared__ int s_lo, s_hi;
  if (tid == 0) {
    int lo = 0, hi = Nn;
    while (lo < hi) { int mid = (lo + hi) >> 1; if (batch[mid] < g) lo = mid + 1; else hi = mid; }
    s_lo = lo;
    int lo2 = lo, hi2 = Nn;
    while (lo2 < hi2) { int mid = (lo2 + hi2) >> 1; if (batch[mid] < g + 1) lo2 = mid + 1; else hi2 = mid; }
    s_hi = lo2;
  }
  __syncthreads();
  int lo = s_lo, hi = s_hi;
  int c = tid & 31, r = tid >> 5;  // 8 row-groups x 32 channels
  float sum = 0.f, mx = -1e30f;
  for (int n = lo + r; n < hi; n += 8) {
    float v = b2f(h3[(size_t)n * 32 + c]);
    sum += v;
    mx = fmaxf(mx, v);
  }
  __shared__ float ssum[8][32];
  __shared__ float smax[8][32];
  ssum[r][c] = sum;
  smax[r][c] = mx;
  __syncthreads();
  __shared__ float z[64];
  __shared__ float zz1[32];
  if (tid < 32) {
    float s = 0.f, m2 = -1e30f;
#pragma unroll
    for (int rr = 0; rr < 8; rr++) { s += ssum[rr][tid]; m2 = fmaxf(m2, smax[rr][tid]); }
    int cnt = hi - lo;
    z[tid] = s / fmaxf((float)cnt, 1.0f);
    z[32 + tid] = (cnt > 0) ? m2 : 0.f;
  }
  __syncthreads();
  if (tid < 32) {
    float s = lb1[tid];
    for (int k = 0; k < 64; k++) s += z[k] * lw1[k * 32 + tid];
    zz1[tid] = fmaxf(s, 0.f);
  }
  __syncthreads();
  if (tid == 0) {
    float s = lb2[0];
    for (int j = 0; j < 32; j++) s += zz1[j] * lw2[j];
    out[g] = 1.f / (1.f + expf(-s));
  }
}

// ---------------- driver ----------------
extern "C" void kernel_launch(void* const* d_in, const int* in_sizes, int n_in,
                              void* d_out, int out_size, void* d_ws, size_t ws_size,
                              hipStream_t stream) {
  const float* x     = (const float*)d_in[0];
  const int*   eidx  = (const int*)d_in[1];
  const float* eattr = (const float*)d_in[2];
  const int*   batch = (const int*)d_in[3];
  int N = in_sizes[0] / 64;
  int E = in_sizes[1] / 2;
  int NG = out_size;
  const int* src = eidx;
  const int* dst = eidx + E;

  const float* W[3]  = {(const float*)d_in[4],  (const float*)d_in[14], (const float*)d_in[24]};
  const float* AS[3] = {(const float*)d_in[5],  (const float*)d_in[15], (const float*)d_in[25]};
  const float* AD[3] = {(const float*)d_in[6],  (const float*)d_in[16], (const float*)d_in[26]};
  const float* WE[3] = {(const float*)d_in[7],  (const float*)d_in[17], (const float*)d_in[27]};
  const float* AE[3] = {(const float*)d_in[8],  (const float*)d_in[18], (const float*)d_in[28]};
  const float* B[3]  = {(const float*)d_in[9],  (const float*)d_in[19], (const float*)d_in[29]};
  const float* G[3]  = {(const float*)d_in[10], (const float*)d_in[20], (const float*)d_in[30]};
  const float* BT[3] = {(const float*)d_in[11], (const float*)d_in[21], (const float*)d_in[31]};
  const float* RM[3] = {(const float*)d_in[12], (const float*)d_in[22], (const float*)d_in[32]};
  const float* RV[3] = {(const float*)d_in[13], (const float*)d_in[23], (const float*)d_in[33]};
  const float* lw1 = (const float*)d_in[34];
  const float* lb1 = (const float*)d_in[35];
  const float* lw2 = (const float*)d_in[36];
  const float* lb2 = (const float*)d_in[37];

  char* wp = (char*)d_ws;
  auto alloc = [&](size_t bytes) -> void* {
    void* p = (void*)wp;
    wp += (bytes + 255) & ~(size_t)255;
    return p;
  };
  u16*   xbf      = (u16*)alloc((size_t)N * 64 * 2);
  u16*   bufH     = (u16*)alloc((size_t)N * 512 * 2);
  u16*   bufA     = (u16*)alloc((size_t)N * 512 * 2);
  u16*   Wt1      = (u16*)alloc((size_t)512 * 64 * 2);
  u16*   Wt2      = (u16*)alloc((size_t)256 * 512 * 2);
  u16*   Wt3      = (u16*)alloc((size_t)32 * 256 * 2);
  int*   degInt   = (int*)alloc((size_t)N * 4);
  int*   cursor   = (int*)alloc((size_t)N * 4);
  int*   rowStart = (int*)alloc((size_t)(N + 1) * 4);
  float* loopAttr = (float*)alloc((size_t)N * 7 * 4);
  int*   csrSrc   = (int*)alloc((size_t)E * 4);
  int*   csrEid   = (int*)alloc((size_t)E * 4);
  float* logitE   = (float*)alloc((size_t)E * 4 * 4);
  float* asrc     = (float*)alloc((size_t)N * 4 * 4);
  float* adst     = (float*)alloc((size_t)N * 4 * 4);
  float* lself    = (float*)alloc((size_t)N * 4 * 4);
  float* watt     = (float*)alloc(32 * 4);

  hipMemsetAsync(degInt, 0, (size_t)N * 4, stream);
  hipMemsetAsync(cursor, 0, (size_t)N * 4, stream);

  // setup
  k_deg<<<(E + 255) / 256, 256, 0, stream>>>(dst, degInt, E);
  k_scan<<<1, 1024, 0, stream>>>(degInt, rowStart, N);
  k_fill_csr<<<(E + 255) / 256, 256, 0, stream>>>(src, dst, rowStart, cursor, csrSrc, csrEid, E);
  k_loop_gather<<<(N * 7 + 255) / 256, 256, 0, stream>>>(rowStart, csrEid, eattr, loopAttr, N);
  k_cast_bf16<<<(N * 64 + 255) / 256, 256, 0, stream>>>(x, xbf, N * 64);
  k_transpose_cast<<<(64 * 512 + 255) / 256, 256, 0, stream>>>(W[0], Wt1, 64, 512);
  k_transpose_cast<<<(512 * 256 + 255) / 256, 256, 0, stream>>>(W[1], Wt2, 512, 256);
  k_transpose_cast<<<(256 * 32 + 255) / 256, 256, 0, stream>>>(W[2], Wt3, 256, 32);

  int gmM = (N + 127) / 128;
  int nb4 = (N + 3) / 4;

  // ---- layer 1: K=64, H=4, C=128, HC=512
  k_gemm_mfma<128, 128, 64, 64><<<dim3(gmM, 4), 256, 0, stream>>>(xbf, Wt1, bufH, N, 64, 512);
  k_attn_nd<<<(N * 4 + 3) / 4, 256, 0, stream>>>(bufH, AS[0], AD[0], asrc, adst, N * 4, 4, 128);
  k_watt<<<1, 64, 0, stream>>>(WE[0], AE[0], watt, 4, 128);
  k_edge_logit<4><<<(E + 255) / 256, 256, 0, stream>>>(src, dst, eattr, asrc, adst, watt, logitE, E);
  k_self_logit<4><<<(N + 255) / 256, 256, 0, stream>>>(loopAttr, watt, asrc, adst, lself, N);
  k_gather4<128, 8><<<nb4, 256, 0, stream>>>(rowStart, csrSrc, csrEid, logitE, lself, bufH,
                                             B[0], G[0], BT[0], RM[0], RV[0], bufA, N);

  // ---- layer 2: K=512, H=4, C=64, HC=256
  k_gemm_mfma<128, 128, 64, 64><<<dim3(gmM, 2), 256, 0, stream>>>(bufA, Wt2, bufH, N, 512, 256);
  k_attn_nd<<<(N * 4 + 3) / 4, 256, 0, stream>>>(bufH, AS[1], AD[1], asrc, adst, N * 4, 4, 64);
  k_watt<<<1, 64, 0, stream>>>(WE[1], AE[1], watt, 4, 64);
  k_edge_logit<4><<<(E + 255) / 256, 256, 0, stream>>>(src, dst, eattr, asrc, adst, watt, logitE, E);
  k_self_logit<4><<<(N + 255) / 256, 256, 0, stream>>>(loopAttr, watt, asrc, adst, lself, N);
  k_gather4<64, 4><<<nb4, 256, 0, stream>>>(rowStart, csrSrc, csrEid, logitE, lself, bufH,
                                            B[1], G[1], BT[1], RM[1], RV[1], bufA, N);

  // ---- layer 3: K=256, H=1, C=32
  k_gemm_mfma<128, 32, 32, 32><<<dim3(gmM, 1), 256, 0, stream>>>(bufA, Wt3, bufH, N, 256, 32);
  k_attn_nd<<<(N + 3) / 4, 256, 0, stream>>>(bufH, AS[2], AD[2], asrc, adst, N, 1, 32);
  k_watt<<<1, 64, 0, stream>>>(WE[2], AE[2], watt, 1, 32);
  k_edge_logit<1><<<(E + 255) / 256, 256, 0, stream>>>(src, dst, eattr, asrc, adst, watt, logitE, E);
  k_self_logit<1><<<(N + 255) / 256, 256, 0, stream>>>(loopAttr, watt, asrc, adst, lself, N);
  k_gather_L3<<<nb4, 256, 0, stream>>>(rowStart, csrSrc, csrEid, logitE, lself, bufH,
                                       B[2], G[2], BT[2], RM[2], RV[2], bufA, N);

  // ---- fused pooling + MLP (sorted batch -> per-group segmented reduce)
  k_pool_mlp<<<NG, 256, 0, stream>>>(bufA, batch, N, lw1, lb1, lw2, lb2, (float*)d_out);
}

// Round 5
// 322.427 us; speedup vs baseline: 2.7497x; 1.1011x over previous
//
#include <hip/hip_runtime.h>
#include <math.h>

#define NEG_SLOPE 0.2f
#define BN_EPS 1e-5f

typedef __attribute__((ext_vector_type(8))) short bf16x8;
typedef __attribute__((ext_vector_type(4))) float f32x4;
typedef unsigned short u16;

static __device__ __forceinline__ float leaky(float v) { return v > 0.f ? v : NEG_SLOPE * v; }
static __device__ __forceinline__ float b2f(u16 b) { return __uint_as_float(((unsigned)b) << 16); }
static __device__ __forceinline__ u16 f2b(float f) {
  unsigned u = __float_as_uint(f);
  u += 0x7FFF + ((u >> 16) & 1);
  return (u16)(u >> 16);
}
static __device__ __forceinline__ float sel4(f32x4 v, int hs) {
  float a = (hs & 1) ? v[1] : v[0];
  float b = (hs & 1) ? v[3] : v[2];
  return (hs & 2) ? b : a;
}

// ---------------- setup ----------------
__global__ void k_deg(const int* __restrict__ dst, int* __restrict__ degInt, int E) {
  int e = blockIdx.x * blockDim.x + threadIdx.x;
  if (e < E) atomicAdd(&degInt[dst[e]], 1);
}

__global__ void k_scan(const int* __restrict__ degInt, int* __restrict__ rowStart, int n) {
  __shared__ int sums[1024];
  int tid = threadIdx.x;
  int per = (n + 1023) / 1024;
  int start = tid * per;
  int end = start + per; if (end > n) end = n;
  int s = 0;
  for (int i = start; i < end; i++) s += degInt[i];
  sums[tid] = s;
  __syncthreads();
  for (int off = 1; off < 1024; off <<= 1) {
    int v = (tid >= off) ? sums[tid - off] : 0;
    __syncthreads();
    sums[tid] += v;
    __syncthreads();
  }
  int base = (tid > 0) ? sums[tid - 1] : 0;
  for (int i = start; i < end; i++) { rowStart[i] = base; base += degInt[i]; }
  if (tid == 1023) rowStart[n] = sums[1023];
}

__global__ void k_fill_csr(const int* __restrict__ src, const int* __restrict__ dst,
                           const int* __restrict__ rowStart, int* __restrict__ cursor,
                           int* __restrict__ csrSrc, int* __restrict__ csrEid,
                           int* __restrict__ posE, int E) {
  int e = blockIdx.x * blockDim.x + threadIdx.x;
  if (e >= E) return;
  int d = dst[e];
  int pos = rowStart[d] + atomicAdd(&cursor[d], 1);
  csrSrc[pos] = src[e];
  csrEid[pos] = e;
  posE[e] = pos;
}

// loopAttr[n][k] = mean of eattr over in-edges (consecutive threads share n, k fastest -> 28B/edge)
__global__ void k_loop_gather(const int* __restrict__ rowStart, const int* __restrict__ csrEid,
                              const float* __restrict__ eattr, float* __restrict__ loopAttr, int Nn) {
  int i = blockIdx.x * blockDim.x + threadIdx.x;
  if (i >= Nn * 7) return;
  int n = i / 7, k = i % 7;
  int r0 = rowStart[n], r1 = rowStart[n + 1];
  float s = 0.f;
  for (int j = r0; j < r1; j++) s += eattr[csrEid[j] * 7 + k];
  loopAttr[i] = s / fmaxf((float)(r1 - r0), 1.0f);
}

// ---------------- casts ----------------
__global__ void k_cast_bf16(const float* __restrict__ in, u16* __restrict__ out, int n) {
  int i = blockIdx.x * blockDim.x + threadIdx.x;
  if (i < n) out[i] = f2b(in[i]);
}

__global__ void k_transpose_cast(const float* __restrict__ W, u16* __restrict__ Wt, int K, int N) {
  int i = blockIdx.x * blockDim.x + threadIdx.x;
  if (i >= K * N) return;
  int k = i / N, n = i % N;
  Wt[(size_t)n * K + k] = f2b(W[i]);
}

// ---------------- MFMA bf16 GEMM: C[M,N] = A[M,K] @ Bt[N,K]^T ----------------
template <int BM, int BN, int WM, int WN>
__global__ __launch_bounds__(256) void k_gemm_mfma(const u16* __restrict__ A,
                                                   const u16* __restrict__ Bt,
                                                   u16* __restrict__ Cout,
                                                   int M, int K, int N) {
  constexpr int BK = 64;
  constexpr int LDT = BK + 8;
  __shared__ u16 As[BM][LDT];
  __shared__ u16 Bs[BN][LDT];
  constexpr int NWN = BN / WN;
  constexpr int M_REP = WM / 16;
  constexpr int N_REP = WN / 16;
  int tid = threadIdx.x;
  int wid = tid >> 6, lane = tid & 63;
  int wr = wid / NWN, wc = wid % NWN;
  int bm = blockIdx.x * BM, bn = blockIdx.y * BN;
  int l15 = lane & 15, l4 = lane >> 4;

  f32x4 acc[M_REP][N_REP];
#pragma unroll
  for (int m = 0; m < M_REP; m++)
#pragma unroll
    for (int n = 0; n < N_REP; n++) acc[m][n] = (f32x4){0.f, 0.f, 0.f, 0.f};

  for (int k0 = 0; k0 < K; k0 += BK) {
    constexpr int CHA = BM * BK / 8;
#pragma unroll
    for (int ch0 = 0; ch0 < CHA; ch0 += 256) {
      int ch = ch0 + tid;
      int row = ch >> 3, cc = (ch & 7) * 8;
      int gr = bm + row;
      bf16x8 v = {};
      if (gr < M) v = *(const bf16x8*)(A + (size_t)gr * K + k0 + cc);
      *(bf16x8*)(&As[row][cc]) = v;
    }
    constexpr int CHB = BN * BK / 8;
#pragma unroll
    for (int ch0 = 0; ch0 < CHB; ch0 += 256) {
      int ch = ch0 + tid;
      int row = ch >> 3, cc = (ch & 7) * 8;
      int gr = bn + row;
      bf16x8 v = {};
      if (gr < N) v = *(const bf16x8*)(Bt + (size_t)gr * K + k0 + cc);
      *(bf16x8*)(&Bs[row][cc]) = v;
    }
    __syncthreads();
#pragma unroll
    for (int ks = 0; ks < BK; ks += 32) {
      bf16x8 af[M_REP], bfr[N_REP];
#pragma unroll
      for (int m = 0; m < M_REP; m++)
        af[m] = *(const bf16x8*)(&As[wr * WM + m * 16 + l15][ks + l4 * 8]);
#pragma unroll
      for (int n = 0; n < N_REP; n++)
        bfr[n] = *(const bf16x8*)(&Bs[wc * WN + n * 16 + l15][ks + l4 * 8]);
#pragma unroll
      for (int m = 0; m < M_REP; m++)
#pragma unroll
        for (int n = 0; n < N_REP; n++)
          acc[m][n] = __builtin_amdgcn_mfma_f32_16x16x32_bf16(af[m], bfr[n], acc[m][n], 0, 0, 0);
    }
    __syncthreads();
  }
#pragma unroll
  for (int m = 0; m < M_REP; m++) {
#pragma unroll
    for (int r = 0; r < 4; r++) {
      int grow = bm + wr * WM + m * 16 + l4 * 4 + r;
      if (grow >= M) continue;
#pragma unroll
      for (int n = 0; n < N_REP; n++) {
        int gcol = bn + wc * WN + n * 16 + l15;
        Cout[(size_t)grow * N + gcol] = f2b(acc[m][n][r]);
      }
    }
  }
}

// ---------------- attention dots, H=4: wave per node, coalesced 16B row loads ----------------
template <int C, int CPL>
__global__ __launch_bounds__(256) void k_attn4(const u16* __restrict__ hbuf,
                                               const float* __restrict__ a_s, const float* __restrict__ a_d,
                                               float* __restrict__ asrc, float* __restrict__ adst, int Nn) {
  constexpr int HC = 4 * C;
  typedef __attribute__((ext_vector_type(CPL))) unsigned short u16v;
  int n = blockIdx.x * 4 + (threadIdx.x >> 6);
  if (n >= Nn) return;
  int lane = threadIdx.x & 63;
  int hs = lane >> 4, l15 = lane & 15;
  u16v hv = *(const u16v*)(hbuf + (size_t)n * HC + lane * CPL);
  float s1 = 0.f, s2 = 0.f;
#pragma unroll
  for (int jj = 0; jj < CPL; jj++) {
    float v = b2f(hv[jj]);
    int c = lane * CPL + jj;  // == hs*C + within-head offset
    s1 += v * a_s[c];
    s2 += v * a_d[c];
  }
#pragma unroll
  for (int off = 1; off < 16; off <<= 1) { s1 += __shfl_xor(s1, off); s2 += __shfl_xor(s2, off); }
  if (l15 == 0) { asrc[n * 4 + hs] = s1; adst[n * 4 + hs] = s2; }
}

// generic (used for L3, H=1, C=32)
__global__ __launch_bounds__(256) void k_attn_nd(const u16* __restrict__ hbuf,
                                                 const float* __restrict__ a_s, const float* __restrict__ a_d,
                                                 float* __restrict__ asrc, float* __restrict__ adst,
                                                 int total, int H, int C) {
  int idx = blockIdx.x * 4 + (threadIdx.x >> 6);
  if (idx >= total) return;
  int n = idx / H, h = idx % H;
  int lane = threadIdx.x & 63;
  float s1 = 0.f, s2 = 0.f;
  for (int c = lane; c < C; c += 64) {
    float v = b2f(hbuf[(size_t)n * H * C + h * C + c]);
    s1 += v * a_s[h * C + c];
    s2 += v * a_d[h * C + c];
  }
  for (int off = 32; off > 0; off >>= 1) { s1 += __shfl_xor(s1, off); s2 += __shfl_xor(s2, off); }
  if (lane == 0) { asrc[idx] = s1; adst[idx] = s2; }
}

__global__ void k_watt(const float* __restrict__ We, const float* __restrict__ a_e,
                       float* __restrict__ w_att, int H, int C) {
  int t = threadIdx.x;
  if (t >= 7 * H) return;
  int d = t / H, h = t % H;
  float s = 0.f;
  for (int c = 0; c < C; c++) s += We[(size_t)d * H * C + h * C + c] * a_e[h * C + c];
  w_att[d * H + h] = s;
}

// edge logits written in CSR order via posE
template <int H>
__global__ void k_edge_logit(const int* __restrict__ src, const int* __restrict__ dst,
                             const float* __restrict__ eattr, const int* __restrict__ posE,
                             const float* __restrict__ asrc, const float* __restrict__ adst,
                             const float* __restrict__ w_att, float* __restrict__ logitC, int E) {
  int e = blockIdx.x * blockDim.x + threadIdx.x;
  if (e >= E) return;
  float ea[7];
#pragma unroll
  for (int d = 0; d < 7; d++) ea[d] = eattr[e * 7 + d];
  int s = src[e], dn = dst[e];
  int pos = posE[e];
  if (H == 4) {
    f32x4 va = *(const f32x4*)(asrc + s * 4);
    f32x4 vd = *(const f32x4*)(adst + dn * 4);
    f32x4 o;
#pragma unroll
    for (int h = 0; h < 4; h++) {
      float ae = 0.f;
#pragma unroll
      for (int d = 0; d < 7; d++) ae += ea[d] * w_att[d * 4 + h];
      o[h] = leaky(va[h] + vd[h] + ae);
    }
    *(f32x4*)(logitC + (size_t)pos * 4) = o;
  } else {
    float ae = 0.f;
#pragma unroll
    for (int d = 0; d < 7; d++) ae += ea[d] * w_att[d];
    logitC[pos] = leaky(asrc[s] + adst[dn] + ae);
  }
}

// ---------------- gather (H=4): single-pass online softmax, CSR-sequential logits ----------------
template <int C, int CPL>
__global__ __launch_bounds__(256) void k_gather4(
    const int* __restrict__ rowStart, const int* __restrict__ csrSrc,
    const float* __restrict__ logitC, const float* __restrict__ loopAttr,
    const float* __restrict__ w_att, const float* __restrict__ asrc, const float* __restrict__ adst,
    const u16* __restrict__ hbuf, const float* __restrict__ bias,
    const float* __restrict__ bng, const float* __restrict__ bnb,
    const float* __restrict__ bnrm, const float* __restrict__ bnrv,
    u16* __restrict__ outbuf, int Nn) {
  constexpr int HC = 4 * C;
  typedef __attribute__((ext_vector_type(CPL))) unsigned short u16v;
  int wid = threadIdx.x >> 6;
  int n = blockIdx.x * 4 + wid;
  if (n >= Nn) return;
  int lane = threadIdx.x & 63;
  int hs = lane >> 4;
  __shared__ float pbuf[4][64 * 4];
  int r0 = rowStart[n], r1 = rowStart[n + 1];

  // self logits (redundant per lane)
  f32x4 va = *(const f32x4*)(asrc + n * 4);
  f32x4 vd = *(const f32x4*)(adst + n * 4);
  float la[7];
#pragma unroll
  for (int d = 0; d < 7; d++) la[d] = loopAttr[n * 7 + d];
  f32x4 ls;
#pragma unroll
  for (int h = 0; h < 4; h++) {
    float ae = 0.f;
#pragma unroll
    for (int d = 0; d < 7; d++) ae += la[d] * w_att[d * 4 + h];
    ls[h] = leaky(va[h] + vd[h] + ae);
  }

  f32x4 m = ls;
  f32x4 denl = {0.f, 0.f, 0.f, 0.f};
  float acc[CPL];
#pragma unroll
  for (int jj = 0; jj < CPL; jj++) acc[jj] = 0.f;

  const f32x4* L4 = (const f32x4*)logitC;
  for (int base = r0; base < r1; base += 64) {
    int slot = base + lane;
    bool valid = slot < r1;
    f32x4 lg = valid ? L4[slot] : (f32x4){-1e30f, -1e30f, -1e30f, -1e30f};
    int srcl = valid ? csrSrc[slot] : 0;
    // chunk max per head
    f32x4 mc = lg;
#pragma unroll
    for (int off = 1; off < 64; off <<= 1) {
#pragma unroll
      for (int h = 0; h < 4; h++) mc[h] = fmaxf(mc[h], __shfl_xor(mc[h], off));
    }
    // merge into running max; rescale
    f32x4 rr;
#pragma unroll
    for (int h = 0; h < 4; h++) {
      float mn = fmaxf(m[h], mc[h]);
      rr[h] = __expf(m[h] - mn);
      m[h] = mn;
      denl[h] *= rr[h];
    }
    float rrh = sel4(rr, hs);
#pragma unroll
    for (int jj = 0; jj < CPL; jj++) acc[jj] *= rrh;
    // per-edge p (computed once), parked in LDS
    f32x4 ex;
#pragma unroll
    for (int h = 0; h < 4; h++) ex[h] = valid ? __expf(lg[h] - m[h]) : 0.f;
#pragma unroll
    for (int h = 0; h < 4; h++) denl[h] += ex[h];
    *(f32x4*)(&pbuf[wid][lane * 4]) = ex;
    int nv = r1 - base; if (nv > 64) nv = 64;
    int j = 0;
    for (; j + 1 < nv; j += 2) {
      int s0 = __shfl(srcl, j);
      int s1 = __shfl(srcl, j + 1);
      float p0 = pbuf[wid][j * 4 + hs];
      float p1 = pbuf[wid][(j + 1) * 4 + hs];
      u16v h0 = *(const u16v*)(hbuf + (size_t)s0 * HC + lane * CPL);
      u16v h1 = *(const u16v*)(hbuf + (size_t)s1 * HC + lane * CPL);
#pragma unroll
      for (int jj = 0; jj < CPL; jj++) acc[jj] += p0 * b2f(h0[jj]) + p1 * b2f(h1[jj]);
    }
    if (j < nv) {
      int s0 = __shfl(srcl, j);
      float p0 = pbuf[wid][j * 4 + hs];
      u16v h0 = *(const u16v*)(hbuf + (size_t)s0 * HC + lane * CPL);
#pragma unroll
      for (int jj = 0; jj < CPL; jj++) acc[jj] += p0 * b2f(h0[jj]);
    }
  }
  // self loop + final reduce
  f32x4 exs;
#pragma unroll
  for (int h = 0; h < 4; h++) exs[h] = __expf(ls[h] - m[h]);
  f32x4 den;
#pragma unroll
  for (int h = 0; h < 4; h++) {
    float v = denl[h];
#pragma unroll
    for (int off = 1; off < 64; off <<= 1) v += __shfl_xor(v, off);
    den[h] = v + exs[h];
  }
  {
    float ps = sel4(exs, hs);
    u16v hN = *(const u16v*)(hbuf + (size_t)n * HC + lane * CPL);
#pragma unroll
    for (int jj = 0; jj < CPL; jj++) acc[jj] += ps * b2f(hN[jj]);
  }
  float dh = sel4(den, hs);
  u16v ov;
#pragma unroll
  for (int jj = 0; jj < CPL; jj++) {
    int c = lane * CPL + jj;
    float v = acc[jj] / dh + bias[c];
    v = (v - bnrm[c]) * (bng[c] * rsqrtf(bnrv[c] + BN_EPS)) + bnb[c];
    ov[jj] = f2b(fmaxf(v, 0.f));
  }
  *(u16v*)(outbuf + (size_t)n * HC + lane * CPL) = ov;
}

// ---------------- gather (H=1, C=32): sequential logits, inline self-logit ----------------
__global__ __launch_bounds__(256) void k_gather_L3(
    const int* __restrict__ rowStart, const int* __restrict__ csrSrc,
    const float* __restrict__ logitC, const float* __restrict__ loopAttr,
    const float* __restrict__ w_att, const float* __restrict__ asrc, const float* __restrict__ adst,
    const u16* __restrict__ hbuf, const float* __restrict__ bias,
    const float* __restrict__ bng, const float* __restrict__ bnb,
    const float* __restrict__ bnrm, const float* __restrict__ bnrv,
    u16* __restrict__ outbuf, int Nn) {
  int n = blockIdx.x * 4 + (threadIdx.x >> 6);
  if (n >= Nn) return;
  int lane = threadIdx.x & 63;
  int cl = lane & 31, half = lane >> 5;
  int r0 = rowStart[n], r1 = rowStart[n + 1];
  float ae = 0.f;
#pragma unroll
  for (int d = 0; d < 7; d++) ae += loopAttr[n * 7 + d] * w_att[d];
  float ls = leaky(asrc[n] + adst[n] + ae);

  float m = ls;
  for (int j = r0 + lane; j < r1; j += 64) m = fmaxf(m, logitC[j]);
  for (int off = 32; off > 0; off >>= 1) m = fmaxf(m, __shfl_xor(m, off));
  float den = 0.f;
  for (int j = r0 + lane; j < r1; j += 64) den += __expf(logitC[j] - m);
  for (int off = 32; off > 0; off >>= 1) den += __shfl_xor(den, off);
  den += __expf(ls - m);

  float acc = 0.f;
  for (int j = r0 + half; j < r1; j += 2) {
    float p = __expf(logitC[j] - m);
    int s = csrSrc[j];
    acc += p * b2f(hbuf[(size_t)s * 32 + cl]);
  }
  if (half == 0) acc += __expf(ls - m) * b2f(hbuf[(size_t)n * 32 + cl]);
  acc += __shfl_xor(acc, 32);
  if (half == 0) {
    float v = acc / den + bias[cl];
    v = (v - bnrm[cl]) * (bng[cl] * rsqrtf(bnrv[cl] + BN_EPS)) + bnb[cl];
    outbuf[(size_t)n * 32 + cl] = f2b(fmaxf(v, 0.f));
  }
}

// ---------------- fused pooling + MLP (batch sorted -> segmented reduce) ----------------
__global__ __launch_bounds__(256) void k_pool_mlp(
    const u16* __restrict__ h3, const int* __restrict__ batch, int Nn,
    const float* __restrict__ lw1, const float* __restrict__ lb1,
    const float* __restrict__ lw2, const float* __restrict__ lb2,
    float* __restrict__ out) {
  int g = blockIdx.x;
  int tid = threadIdx.x;
  __shared__ int s_lo, s_hi;
  if (tid == 0) {
    int lo = 0, hi = Nn;
    while (lo < hi) { int mid = (lo + hi) >> 1; if (batch[mid] < g) lo = mid + 1; else hi = mid; }
    s_lo = lo;
    int lo2 = lo, hi2 = Nn;
    while (lo2 < hi2) { int mid = (lo2 + hi2) >> 1; if (batch[mid] < g + 1) lo2 = mid + 1; else hi2 = mid; }
    s_hi = lo2;
  }
  __syncthreads();
  int lo = s_lo, hi = s_hi;
  int c = tid & 31, r = tid >> 5;
  float sum = 0.f, mx = -1e30f;
  for (int n = lo + r; n < hi; n += 8) {
    float v = b2f(h3[(size_t)n * 32 + c]);
    sum += v;
    mx = fmaxf(mx, v);
  }
  __shared__ float ssum[8][32];
  __shared__ float smax[8][32];
  ssum[r][c] = sum;
  smax[r][c] = mx;
  __syncthreads();
  __shared__ float z[64];
  __shared__ float zz1[32];
  if (tid < 32) {
    float s = 0.f, m2 = -1e30f;
#pragma unroll
    for (int rr = 0; rr < 8; rr++) { s += ssum[rr][tid]; m2 = fmaxf(m2, smax[rr][tid]); }
    int cnt = hi - lo;
    z[tid] = s / fmaxf((float)cnt, 1.0f);
    z[32 + tid] = (cnt > 0) ? m2 : 0.f;
  }
  __syncthreads();
  if (tid < 32) {
    float s = lb1[tid];
    for (int k = 0; k < 64; k++) s += z[k] * lw1[k * 32 + tid];
    zz1[tid] = fmaxf(s, 0.f);
  }
  __syncthreads();
  if (tid == 0) {
    float s = lb2[0];
    for (int j = 0; j < 32; j++) s += zz1[j] * lw2[j];
    out[g] = 1.f / (1.f + expf(-s));
  }
}

// ---------------- driver ----------------
extern "C" void kernel_launch(void* const* d_in, const int* in_sizes, int n_in,
                              void* d_out, int out_size, void* d_ws, size_t ws_size,
                              hipStream_t stream) {
  const float* x     = (const float*)d_in[0];
  const int*   eidx  = (const int*)d_in[1];
  const float* eattr = (const float*)d_in[2];
  const int*   batch = (const int*)d_in[3];
  int N = in_sizes[0] / 64;
  int E = in_sizes[1] / 2;
  int NG = out_size;
  const int* src = eidx;
  const int* dst = eidx + E;

  const float* W[3]  = {(const float*)d_in[4],  (const float*)d_in[14], (const float*)d_in[24]};
  const float* AS[3] = {(const float*)d_in[5],  (const float*)d_in[15], (const float*)d_in[25]};
  const float* AD[3] = {(const float*)d_in[6],  (const float*)d_in[16], (const float*)d_in[26]};
  const float* WE[3] = {(const float*)d_in[7],  (const float*)d_in[17], (const float*)d_in[27]};
  const float* AE[3] = {(const float*)d_in[8],  (const float*)d_in[18], (const float*)d_in[28]};
  const float* B[3]  = {(const float*)d_in[9],  (const float*)d_in[19], (const float*)d_in[29]};
  const float* G[3]  = {(const float*)d_in[10], (const float*)d_in[20], (const float*)d_in[30]};
  const float* BT[3] = {(const float*)d_in[11], (const float*)d_in[21], (const float*)d_in[31]};
  const float* RM[3] = {(const float*)d_in[12], (const float*)d_in[22], (const float*)d_in[32]};
  const float* RV[3] = {(const float*)d_in[13], (const float*)d_in[23], (const float*)d_in[33]};
  const float* lw1 = (const float*)d_in[34];
  const float* lb1 = (const float*)d_in[35];
  const float* lw2 = (const float*)d_in[36];
  const float* lb2 = (const float*)d_in[37];

  char* wp = (char*)d_ws;
  auto alloc = [&](size_t bytes) -> void* {
    void* p = (void*)wp;
    wp += (bytes + 255) & ~(size_t)255;
    return p;
  };
  u16*   xbf      = (u16*)alloc((size_t)N * 64 * 2);
  u16*   bufH     = (u16*)alloc((size_t)N * 512 * 2);
  u16*   bufA     = (u16*)alloc((size_t)N * 512 * 2);
  u16*   Wt1      = (u16*)alloc((size_t)512 * 64 * 2);
  u16*   Wt2      = (u16*)alloc((size_t)256 * 512 * 2);
  u16*   Wt3      = (u16*)alloc((size_t)32 * 256 * 2);
  int*   degInt   = (int*)alloc((size_t)N * 4);
  int*   cursor   = (int*)alloc((size_t)N * 4);
  int*   rowStart = (int*)alloc((size_t)(N + 1) * 4);
  float* loopAttr = (float*)alloc((size_t)N * 7 * 4);
  int*   csrSrc   = (int*)alloc((size_t)E * 4);
  int*   csrEid   = (int*)alloc((size_t)E * 4);
  int*   posE     = (int*)alloc((size_t)E * 4);
  float* logitC   = (float*)alloc((size_t)E * 4 * 4);
  float* asrc     = (float*)alloc((size_t)N * 4 * 4);
  float* adst     = (float*)alloc((size_t)N * 4 * 4);
  float* watt     = (float*)alloc(32 * 4);

  hipMemsetAsync(degInt, 0, (size_t)N * 4, stream);
  hipMemsetAsync(cursor, 0, (size_t)N * 4, stream);

  // setup
  k_deg<<<(E + 255) / 256, 256, 0, stream>>>(dst, degInt, E);
  k_scan<<<1, 1024, 0, stream>>>(degInt, rowStart, N);
  k_fill_csr<<<(E + 255) / 256, 256, 0, stream>>>(src, dst, rowStart, cursor, csrSrc, csrEid, posE, E);
  k_loop_gather<<<(N * 7 + 255) / 256, 256, 0, stream>>>(rowStart, csrEid, eattr, loopAttr, N);
  k_cast_bf16<<<(N * 64 + 255) / 256, 256, 0, stream>>>(x, xbf, N * 64);
  k_transpose_cast<<<(64 * 512 + 255) / 256, 256, 0, stream>>>(W[0], Wt1, 64, 512);
  k_transpose_cast<<<(512 * 256 + 255) / 256, 256, 0, stream>>>(W[1], Wt2, 512, 256);
  k_transpose_cast<<<(256 * 32 + 255) / 256, 256, 0, stream>>>(W[2], Wt3, 256, 32);

  int gmM = (N + 127) / 128;
  int nb4 = (N + 3) / 4;

  // ---- layer 1: K=64, H=4, C=128, HC=512
  k_gemm_mfma<128, 128, 64, 64><<<dim3(gmM, 4), 256, 0, stream>>>(xbf, Wt1, bufH, N, 64, 512);
  k_attn4<128, 8><<<nb4, 256, 0, stream>>>(bufH, AS[0], AD[0], asrc, adst, N);
  k_watt<<<1, 64, 0, stream>>>(WE[0], AE[0], watt, 4, 128);
  k_edge_logit<4><<<(E + 255) / 256, 256, 0, stream>>>(src, dst, eattr, posE, asrc, adst, watt, logitC, E);
  k_gather4<128, 8><<<nb4, 256, 0, stream>>>(rowStart, csrSrc, logitC, loopAttr, watt, asrc, adst,
                                             bufH, B[0], G[0], BT[0], RM[0], RV[0], bufA, N);

  // ---- layer 2: K=512, H=4, C=64, HC=256
  k_gemm_mfma<128, 128, 64, 64><<<dim3(gmM, 2), 256, 0, stream>>>(bufA, Wt2, bufH, N, 512, 256);
  k_attn4<64, 4><<<nb4, 256, 0, stream>>>(bufH, AS[1], AD[1], asrc, adst, N);
  k_watt<<<1, 64, 0, stream>>>(WE[1], AE[1], watt, 4, 64);
  k_edge_logit<4><<<(E + 255) / 256, 256, 0, stream>>>(src, dst, eattr, posE, asrc, adst, watt, logitC, E);
  k_gather4<64, 4><<<nb4, 256, 0, stream>>>(rowStart, csrSrc, logitC, loopAttr, watt, asrc, adst,
                                            bufH, B[1], G[1], BT[1], RM[1], RV[1], bufA, N);

  // ---- layer 3: K=256, H=1, C=32
  k_gemm_mfma<128, 32, 32, 32><<<dim3(gmM, 1), 256, 0, stream>>>(bufA, Wt3, bufH, N, 256, 32);
  k_attn_nd<<<(N + 3) / 4, 256, 0, stream>>>(bufH, AS[2], AD[2], asrc, adst, N, 1, 32);
  k_watt<<<1, 64, 0, stream>>>(WE[2], AE[2], watt, 1, 32);
  k_edge_logit<1><<<(E + 255) / 256, 256, 0, stream>>>(src, dst, eattr, posE, asrc, adst, watt, logitC, E);
  k_gather_L3<<<nb4, 256, 0, stream>>>(rowStart, csrSrc, logitC, loopAttr, watt, asrc, adst,
                                       bufH, B[2], G[2], BT[2], RM[2], RV[2], bufA, N);

  // ---- fused pooling + MLP
  k_pool_mlp<<<NG, 256, 0, stream>>>(bufA, batch, N, lw1, lb1, lw2, lb2, (float*)d_out);
}